// Round 8
// baseline (6922.410 us; speedup 1.0000x reference)
//
#include <hip/hip_runtime.h>
#include <hip/hip_bf16.h>
#include <math.h>

// Problem constants
#define VV   32000
#define DD   300
#define HU   300
#define NC   3
#define BB   128
#define TT   512
#define N4H  1200
#define CHUNK 64
#define NCHUNK (TT / CHUNK)

// Recurrent kernel partition
#define GC   15   // col groups (units)
#define GR   16   // row groups
#define RPW  8    // rows per WG (BB/GR)
#define UPW  20   // units per WG (HU/GC)
#define KSW  96   // k-window per wave (4 waves x 96 covers 300 w/ zero pad)
#define HLB_STRIDE 312            // h plane row stride in shorts (624B: 16B-aligned, 2-way bank alias = free)
#define HLB_SIZE   (16 * HLB_STRIDE + 32)

// Workspace layout: [zx (float)][ex (ulong, tagged h exchange)][cst][hfin]
static constexpr size_t ZX_F   = (size_t)BB * CHUNK * N4H;   // 9,830,400 floats
static constexpr size_t EX_W   = (size_t)2 * GR * RPW * HU;  // 76,800 ulongs
static constexpr size_t CST_F  = (size_t)BB * HU;            // 38,400 floats
static constexpr size_t HFIN_F = (size_t)BB * HU;            // 38,400 floats

typedef __attribute__((ext_vector_type(8))) short bf16x8;
typedef __attribute__((ext_vector_type(4))) float f32x4;
typedef unsigned long long ull;

__device__ __forceinline__ short f2bf(float f) {
    unsigned u = __float_as_uint(f);
    u += 0x7fff + ((u >> 16) & 1);   // round-to-nearest-even
    return (short)(u >> 16);
}
__device__ __forceinline__ float bf2f(short s) {
    return __uint_as_float(((unsigned)(unsigned short)s) << 16);
}
__device__ __forceinline__ float sigm(float x) { return 1.f / (1.f + __expf(-x)); }
__device__ __forceinline__ float tanh_(float x) { return 1.f - 2.f / (__expf(2.f * x) + 1.f); }

// ---------------------------------------------------------------------------
// init: zero exchange tags, c state, out[0]  (ws is poisoned 0xAA every launch)
// ---------------------------------------------------------------------------
__global__ void init_kernel(ull* __restrict__ ex, float* __restrict__ cst,
                            float* __restrict__ out) {
    size_t i = (size_t)blockIdx.x * 256 + threadIdx.x;
    if (i < EX_W) ex[i] = 0ull;
    if (i < CST_F) cst[i] = 0.f;
    if (i == 0) out[0] = 0.f;
}

// ---------------------------------------------------------------------------
// Phase 1: zx[b][tc][n] = emb[ids[b][t0+tc]] @ W_lstm[0:300] + b_lstm   (bf16 MFMA)
// WG tile: M=256 rows, N=80 cols, K=320 (300 zero-padded). 4 waves, wave = 64x80.
// grid = (8192/256, 1200/80) = (32, 15)
// ---------------------------------------------------------------------------
__global__ __launch_bounds__(256) void zx_gemm(
    const float* __restrict__ emb, const int* __restrict__ ids,
    const float* __restrict__ Wl, const float* __restrict__ bl,
    float* __restrict__ zx, int t0)
{
    __shared__ short A_l[256 * 40];   // [row][k] pad 32->40 shorts
    __shared__ short B_l[80 * 40];    // [col][k] (transposed)
    __shared__ int   ids_l[256];

    const int tid = threadIdx.x;
    const int m0  = blockIdx.x * 256;
    const int n0  = blockIdx.y * 80;
    const int wv  = tid >> 6, ln = tid & 63;

    {   // per-row embedding id
        int m = m0 + tid;
        int b = m >> 6, tc = m & (CHUNK - 1);
        ids_l[tid] = ids[b * TT + t0 + tc];
    }

    f32x4 acc[4][5];
    for (int i = 0; i < 4; ++i)
        for (int j = 0; j < 5; ++j)
            acc[i][j] = (f32x4){0.f, 0.f, 0.f, 0.f};

    for (int k0 = 0; k0 < 320; k0 += 32) {
        __syncthreads();
        // stage A: 256 rows x 32 k, one row per thread (float4 x8, guard k<300)
        {
            const float* src = emb + (size_t)ids_l[tid] * DD;
            #pragma unroll
            for (int q = 0; q < 8; ++q) {
                int kg = k0 + q * 4;
                float4 v;
                if (kg < DD) v = *(const float4*)(src + kg);
                else         v = make_float4(0.f, 0.f, 0.f, 0.f);
                short4 s; s.x = f2bf(v.x); s.y = f2bf(v.y); s.z = f2bf(v.z); s.w = f2bf(v.w);
                *(short4*)&A_l[tid * 40 + q * 4] = s;
            }
        }
        // stage B (transposed): 80 cols x 32 k. thread: kk=tid>>3, 10 cols each
        {
            int kk = tid >> 3;
            int c0 = (tid & 7) * 10;
            int kg = k0 + kk;
            #pragma unroll
            for (int c = 0; c < 10; ++c) {
                float v = (kg < DD) ? Wl[(size_t)kg * N4H + n0 + c0 + c] : 0.f;
                B_l[(c0 + c) * 40 + kk] = f2bf(v);
            }
        }
        __syncthreads();
        // fragments + MFMA. A[m=lane&15][k=quad*8+j], B[k=quad*8+j][n=lane&15]
        const int koff = (ln >> 4) * 8;
        bf16x8 afr[4], bfr[5];
        #pragma unroll
        for (int mt = 0; mt < 4; ++mt) {
            int row = wv * 64 + mt * 16 + (ln & 15);
            afr[mt] = *(const bf16x8*)&A_l[row * 40 + koff];
        }
        #pragma unroll
        for (int nt = 0; nt < 5; ++nt) {
            int col = nt * 16 + (ln & 15);
            bfr[nt] = *(const bf16x8*)&B_l[col * 40 + koff];
        }
        #pragma unroll
        for (int mt = 0; mt < 4; ++mt)
            #pragma unroll
            for (int nt = 0; nt < 5; ++nt)
                acc[mt][nt] = __builtin_amdgcn_mfma_f32_16x16x32_bf16(
                    afr[mt], bfr[nt], acc[mt][nt], 0, 0, 0);
    }
    // epilogue: C row=(lane>>4)*4+reg, col=lane&15; add bias
    #pragma unroll
    for (int mt = 0; mt < 4; ++mt) {
        #pragma unroll
        for (int nt = 0; nt < 5; ++nt) {
            #pragma unroll
            for (int rg = 0; rg < 4; ++rg) {
                int row = m0 + wv * 64 + mt * 16 + (ln >> 4) * 4 + rg;
                int col = n0 + nt * 16 + (ln & 15);
                zx[(size_t)row * N4H + col] = acc[mt][nt][rg] + bl[col];
            }
        }
    }
}

// ---------------------------------------------------------------------------
// Phase 2: persistent recurrent kernel. 240 WGs = 16 row-groups x 15 col-groups.
// Recurrent GEMM is SPLIT-PRECISION bf16 MFMA (fp32-grade accuracy):
//   x = x_hi + x_lo (hi = bf16(x), lo = bf16(x - hi), residual ~2^-17)
//   z = h_hi@W_hi + h_hi@W_lo + h_lo@W_hi   (lo*lo ~2^-18 dropped)
// M=16 (8 real + 8 pad rows), N=80 (5 tiles), K split across waves (wave w
// owns k in [96w,96w+96); wave 3 has 288..299 real, rest zero). W_h lives as
// 2x15 pre-packed bf16 B-fragments in registers (120 VGPRs/lane), pinned by
// in-loop asm. h staged in 2 LDS planes (hi/lo); c/h_old carried in gate-lane
// fp32 registers; fp32 h crosses WGs in the tagged words (no recurrent
// precision loss in state carry).
//
// NaN guard (R6): both h planes zeroed IN FULL once per dispatch, so wave 3's
// A reads of cols 300..319 are exact 0 (B is 0 there too; 0*0 = 0, no NaN).
//
// Sync unchanged from R5: one-way tagged-word exchange, coalesced batched poll.
// Hazard closure: MFMA-read(t) < zp-barrier(t) < poll-write(t+1); post-poll
// barrier(t+1) separates gate zp-reads(t) from zp-writes(t+1).
// ---------------------------------------------------------------------------
__global__ __launch_bounds__(256, 1) void lstm_rec(
    const float* __restrict__ zx, const float* __restrict__ Wl,
    const int* __restrict__ lens, ull* __restrict__ ex,
    float* __restrict__ cst, float* __restrict__ hfin, int t0)
{
    const int tid = threadIdx.x;
    const int wv  = tid >> 6, ln = tid & 63;
    const int rg  = blockIdx.x % GR;
    const int cgi = blockIdx.x / GR;
    const int r0  = rg * RPW;
    const int u0  = cgi * UPW;
    const int m   = ln & 15;           // MFMA row / col-in-tile
    const int quad = ln >> 4;

    // ---- one-time: pack W_h hi/lo B-fragments for this wave's k-window ----
    // B[k=quad*8+j][n=lane&15]; frag f = s*5+nt covers kstep s, ntile nt.
    bf16x8 bhi[15], blo[15];
    #pragma unroll
    for (int s = 0; s < 3; ++s) {
        #pragma unroll
        for (int nt = 0; nt < 5; ++nt) {
            int c    = nt * 16 + m;            // 0..79 within WG cols
            int gate = c / 20;
            int wcol = 300 * gate + u0 + (c % 20);
            bf16x8 bh, bl2;
            #pragma unroll
            for (int j = 0; j < 8; ++j) {
                int k = KSW * wv + 32 * s + quad * 8 + j;
                float v = (k < HU) ? Wl[(size_t)(DD + k) * N4H + wcol] : 0.f;
                short hi = f2bf(v);
                short lo = f2bf(v - bf2f(hi));
                bh[j] = hi; bl2[j] = lo;
            }
            bhi[s * 5 + nt] = bh;
            blo[s * 5 + nt] = bl2;
        }
    }
    const int nks = (wv == 3) ? 1 : 3;   // wave 3: only kstep 0 has real k

    __shared__ short h_hi[HLB_SIZE];        // bf16 hi plane of h_{t-1}
    __shared__ short h_lo[HLB_SIZE];        // bf16 lo plane of h_{t-1}
    __shared__ float zp[4][RPW][84];        // per-wave k-partials (pad 80->84)

    // zero BOTH planes in full once per dispatch (NaN guard, see header)
    for (int i = tid; i < HLB_SIZE; i += 256) { h_hi[i] = 0; h_lo[i] = 0; }

    // gate role (tid < 160): u = tid%20, r = tid/20; c/h_old in registers
    const int g_u = tid % UPW, g_r = tid / UPW;
    const bool gl = (tid < RPW * UPW);
    float c_reg = 0.f, ho_reg = 0.f;
    int mylen = 0;
    if (gl) {
        c_reg = cst[(size_t)(r0 + g_r) * HU + u0 + g_u];
        mylen = lens[r0 + g_r];
        if (t0 > 0) {   // reload own h_{t0-1} (tag t0, parity t0&1) from last dispatch
            ull v = __hip_atomic_load(
                ex + (((size_t)(t0 & 1) * GR + rg) * RPW + g_r) * HU + u0 + g_u,
                __ATOMIC_RELAXED, __HIP_MEMORY_SCOPE_AGENT);
            ho_reg = __uint_as_float((unsigned)v);
        }
    }
    __syncthreads();   // zero-init visible before first poll writes

    for (int tc = 0; tc < CHUNK; ++tc) {
        const int t = t0 + tc;

        // pin B-fragments in VGPRs (empty asm: no insts, blocks remat/spill)
        #pragma unroll
        for (int f = 0; f < 15; ++f) {
            int4& qh = *(int4*)&bhi[f];
            asm volatile("" : "+v"(qh.x), "+v"(qh.y), "+v"(qh.z), "+v"(qh.w));
            int4& ql = *(int4*)&blo[f];
            asm volatile("" : "+v"(ql.x), "+v"(ql.y), "+v"(ql.z), "+v"(ql.w));
        }

        // prefetch zx for this step (independent of h)
        float z_pre[4];
        if (gl) {
            const float* zrow = zx + ((size_t)(r0 + g_r) * CHUNK + tc) * N4H;
            #pragma unroll
            for (int gg = 0; gg < 4; ++gg)
                z_pre[gg] = zrow[300 * gg + u0 + g_u];
        }

        // ---- stage h_{t-1} hi/lo: coalesced batched tagged poll ----
        if (t == 0) {
            for (int i = tid; i < RPW * HU; i += 256) {
                int idx = (i / HU) * HLB_STRIDE + (i % HU);
                h_hi[idx] = 0; h_lo[idx] = 0;
            }
        } else {
            const ull* exb = ex + ((size_t)(t & 1) * GR + rg) * (RPW * HU);
            unsigned pend = (tid < (RPW * HU - 9 * 256)) ? 0x3FFu : 0x1FFu;
            do {
                ull v[10];
                #pragma unroll
                for (int k = 0; k < 10; ++k)
                    if ((pend >> k) & 1)
                        v[k] = __hip_atomic_load(exb + tid + (k << 8),
                                                 __ATOMIC_RELAXED,
                                                 __HIP_MEMORY_SCOPE_AGENT);
                unsigned got = 0;
                #pragma unroll
                for (int k = 0; k < 10; ++k) {
                    if (((pend >> k) & 1) && (int)(v[k] >> 32) >= t) {
                        int i = tid + (k << 8);
                        int idx = (i / HU) * HLB_STRIDE + (i % HU);
                        float f = __uint_as_float((unsigned)v[k]);
                        short hi = f2bf(f);
                        h_hi[idx] = hi;
                        h_lo[idx] = f2bf(f - bf2f(hi));
                        got |= 1u << k;
                    }
                }
                pend &= ~got;
                if (pend) __builtin_amdgcn_s_sleep(1);
            } while (pend);
        }
        __syncthreads();

        // ---- MFMA: A hi/lo from LDS, B hi/lo from registers, 3 products ----
        f32x4 acc[5];
        #pragma unroll
        for (int nt = 0; nt < 5; ++nt) acc[nt] = (f32x4){0.f, 0.f, 0.f, 0.f};
        for (int s = 0; s < nks; ++s) {
            const int aoff = m * HLB_STRIDE + KSW * wv + 32 * s + quad * 8;
            bf16x8 ah = *(const bf16x8*)&h_hi[aoff];
            bf16x8 al = *(const bf16x8*)&h_lo[aoff];
            #pragma unroll
            for (int nt = 0; nt < 5; ++nt)
                acc[nt] = __builtin_amdgcn_mfma_f32_16x16x32_bf16(
                    ah, bhi[s * 5 + nt], acc[nt], 0, 0, 0);
            #pragma unroll
            for (int nt = 0; nt < 5; ++nt)
                acc[nt] = __builtin_amdgcn_mfma_f32_16x16x32_bf16(
                    ah, blo[s * 5 + nt], acc[nt], 0, 0, 0);
            #pragma unroll
            for (int nt = 0; nt < 5; ++nt)
                acc[nt] = __builtin_amdgcn_mfma_f32_16x16x32_bf16(
                    al, bhi[s * 5 + nt], acc[nt], 0, 0, 0);
        }
        // C: row=quad*4+reg (lanes 0-31 -> rows 0-7), col=nt*16+m
        if (ln < 32) {
            #pragma unroll
            for (int nt = 0; nt < 5; ++nt)
                #pragma unroll
                for (int r4 = 0; r4 < 4; ++r4)
                    zp[wv][quad * 4 + r4][nt * 16 + m] = acc[nt][r4];
        }
        __syncthreads();

        // ---- reduce 4 partials + gates + tagged publish (160 threads) ----
        if (gl) {
            const int b = r0 + g_r;
            float z4[4];
            #pragma unroll
            for (int gg = 0; gg < 4; ++gg) {
                int cidx = gg * UPW + g_u;
                z4[gg] = z_pre[gg] + zp[0][g_r][cidx] + zp[1][g_r][cidx]
                                   + zp[2][g_r][cidx] + zp[3][g_r][cidx];
            }
            float ig = sigm(z4[0]);
            float jg = tanh_(z4[1]);
            float fg = sigm(z4[2] + 1.0f);   // FORGET_BIAS
            float og = sigm(z4[3]);
            float c_new = c_reg * fg + ig * jg;
            float h_new = tanh_(c_new) * og;
            bool upd = (t < mylen);
            ho_reg = upd ? h_new : ho_reg;
            c_reg  = upd ? c_new : c_reg;
            // publish h_t (tag t+1, parity (t+1)&1) — fire & forget
            ull pk = ((ull)(unsigned)(t + 1) << 32) | (ull)__float_as_uint(ho_reg);
            __hip_atomic_store(
                ex + (((size_t)((t + 1) & 1) * GR + rg) * RPW + g_r) * HU + u0 + g_u,
                pk, __ATOMIC_RELAXED, __HIP_MEMORY_SCOPE_AGENT);
            if (tc == CHUNK - 1) hfin[(size_t)b * HU + u0 + g_u] = ho_reg;
        }
        // no trailing barrier: poll-accept of t+1 requires own publish (self is
        // a producer), which orders all zp/h-plane reuse.
    }
    if (gl) cst[(size_t)(r0 + g_r) * HU + u0 + g_u] = c_reg;
}

// ---------------------------------------------------------------------------
// Phase 3: logits = h_final @ W_dense + b_dense; log-softmax NLL; mean loss.
// One wave per batch row.
// ---------------------------------------------------------------------------
__global__ __launch_bounds__(64) void cls_kernel(
    const float* __restrict__ hfin, const float* __restrict__ Wd,
    const float* __restrict__ bd, const int* __restrict__ labels,
    float* __restrict__ out)
{
    const int b = blockIdx.x;
    const int ln = threadIdx.x;
    const float* h = hfin + (size_t)b * HU;
    float p0 = 0.f, p1 = 0.f, p2 = 0.f;
    for (int k = ln; k < HU; k += 64) {
        float hv = h[k];
        p0 += hv * Wd[k * 3 + 0];
        p1 += hv * Wd[k * 3 + 1];
        p2 += hv * Wd[k * 3 + 2];
    }
    #pragma unroll
    for (int off = 32; off > 0; off >>= 1) {
        p0 += __shfl_down(p0, off);
        p1 += __shfl_down(p1, off);
        p2 += __shfl_down(p2, off);
    }
    if (ln == 0) {
        float l0 = p0 + bd[0], l1 = p1 + bd[1], l2 = p2 + bd[2];
        float m = fmaxf(l0, fmaxf(l1, l2));
        float lse = m + logf(__expf(l0 - m) + __expf(l1 - m) + __expf(l2 - m));
        int lab = labels[b];
        float sel = (lab == 0) ? l0 : ((lab == 1) ? l1 : l2);
        float nll = lse - sel;
        out[1 + b * 3 + 0] = l0;
        out[1 + b * 3 + 1] = l1;
        out[1 + b * 3 + 2] = l2;
        atomicAdd(out, nll * (1.0f / BB));
    }
}

// ---------------------------------------------------------------------------
extern "C" void kernel_launch(void* const* d_in, const int* in_sizes, int n_in,
                              void* d_out, int out_size, void* d_ws, size_t ws_size,
                              hipStream_t stream) {
    const int*   ids  = (const int*)d_in[0];
    const int*   lens = (const int*)d_in[1];
    const int*   labs = (const int*)d_in[2];
    const float* emb  = (const float*)d_in[3];
    const float* Wl   = (const float*)d_in[4];
    const float* bl   = (const float*)d_in[5];
    const float* Wd   = (const float*)d_in[6];
    const float* bd   = (const float*)d_in[7];
    float* out = (float*)d_out;

    float* zx   = (float*)d_ws;
    ull*   ex   = (ull*)(zx + ZX_F);
    float* cst  = (float*)(ex + EX_W);
    float* hfin = cst + CST_F;

    {   // zero exchange tags / c state / out[0]
        int n = (int)((EX_W + 255) / 256);
        init_kernel<<<n, 256, 0, stream>>>(ex, cst, out);
    }
    for (int c = 0; c < NCHUNK; ++c) {
        int t0 = c * CHUNK;
        zx_gemm<<<dim3(32, 15), 256, 0, stream>>>(emb, ids, Wl, bl, zx, t0);
        lstm_rec<<<GR * GC, 256, 0, stream>>>(zx, Wl, lens, ex, cst, hfin, t0);
    }
    cls_kernel<<<BB, 64, 0, stream>>>(hfin, Wd, bd, labs, out);
}

// Round 9
// 4079.364 us; speedup vs baseline: 1.6969x; 1.6969x over previous
//
#include <hip/hip_runtime.h>
#include <hip/hip_bf16.h>
#include <math.h>

// Problem constants
#define VV   32000
#define DD   300
#define HU   300
#define NC   3
#define BB   128
#define TT   512
#define N4H  1200
#define CHUNK 64
#define NCHUNK (TT / CHUNK)

// Recurrent kernel partition
#define GC   15   // col groups (units)
#define GR   16   // row groups
#define RPW  8    // rows per WG (BB/GR)
#define UPW  20   // units per WG (HU/GC)
#define KSW  96   // k-window per wave (4 waves x 96 covers 300 w/ zero pad)
#define HLB_STRIDE 312            // h plane row stride in shorts (624B: 16B-aligned, 2-way bank alias = free)
#define HLB_SIZE   (16 * HLB_STRIDE + 32)

// Workspace layout: [zx (float)][ex (ulong, tagged h exchange)][cst][hfin]
static constexpr size_t ZX_F   = (size_t)BB * CHUNK * N4H;   // 9,830,400 floats
static constexpr size_t EX_W   = (size_t)2 * GR * RPW * HU;  // 76,800 ulongs
static constexpr size_t CST_F  = (size_t)BB * HU;            // 38,400 floats
static constexpr size_t HFIN_F = (size_t)BB * HU;            // 38,400 floats

typedef __attribute__((ext_vector_type(8))) short bf16x8;
typedef __attribute__((ext_vector_type(8))) _Float16 f16x8;
typedef __attribute__((ext_vector_type(4))) float f32x4;
typedef unsigned long long ull;

__device__ __forceinline__ short f2bf(float f) {
    unsigned u = __float_as_uint(f);
    u += 0x7fff + ((u >> 16) & 1);   // round-to-nearest-even
    return (short)(u >> 16);
}
__device__ __forceinline__ short f2h(float f) {   // float -> f16 bits (RTNE)
    _Float16 h = (_Float16)f;
    return *(short*)&h;
}
__device__ __forceinline__ float h2f(short s) {
    _Float16 h = *(_Float16*)&s;
    return (float)h;
}
__device__ __forceinline__ float sigm(float x) { return 1.f / (1.f + __expf(-x)); }
__device__ __forceinline__ float tanh_(float x) { return 1.f - 2.f / (__expf(2.f * x) + 1.f); }

// ---------------------------------------------------------------------------
// init: zero exchange tags, c state, out[0]  (ws is poisoned 0xAA every launch)
// ---------------------------------------------------------------------------
__global__ void init_kernel(ull* __restrict__ ex, float* __restrict__ cst,
                            float* __restrict__ out) {
    size_t i = (size_t)blockIdx.x * 256 + threadIdx.x;
    if (i < EX_W) ex[i] = 0ull;
    if (i < CST_F) cst[i] = 0.f;
    if (i == 0) out[0] = 0.f;
}

// ---------------------------------------------------------------------------
// Phase 1: zx[b][tc][n] = emb[ids[b][t0+tc]] @ W_lstm[0:300] + b_lstm   (bf16 MFMA)
// WG tile: M=256 rows, N=80 cols, K=320 (300 zero-padded). 4 waves, wave = 64x80.
// grid = (8192/256, 1200/80) = (32, 15)
// ---------------------------------------------------------------------------
__global__ __launch_bounds__(256) void zx_gemm(
    const float* __restrict__ emb, const int* __restrict__ ids,
    const float* __restrict__ Wl, const float* __restrict__ bl,
    float* __restrict__ zx, int t0)
{
    __shared__ short A_l[256 * 40];   // [row][k] pad 32->40 shorts
    __shared__ short B_l[80 * 40];    // [col][k] (transposed)
    __shared__ int   ids_l[256];

    const int tid = threadIdx.x;
    const int m0  = blockIdx.x * 256;
    const int n0  = blockIdx.y * 80;
    const int wv  = tid >> 6, ln = tid & 63;

    {   // per-row embedding id
        int m = m0 + tid;
        int b = m >> 6, tc = m & (CHUNK - 1);
        ids_l[tid] = ids[b * TT + t0 + tc];
    }

    f32x4 acc[4][5];
    for (int i = 0; i < 4; ++i)
        for (int j = 0; j < 5; ++j)
            acc[i][j] = (f32x4){0.f, 0.f, 0.f, 0.f};

    for (int k0 = 0; k0 < 320; k0 += 32) {
        __syncthreads();
        // stage A: 256 rows x 32 k, one row per thread (float4 x8, guard k<300)
        {
            const float* src = emb + (size_t)ids_l[tid] * DD;
            #pragma unroll
            for (int q = 0; q < 8; ++q) {
                int kg = k0 + q * 4;
                float4 v;
                if (kg < DD) v = *(const float4*)(src + kg);
                else         v = make_float4(0.f, 0.f, 0.f, 0.f);
                short4 s; s.x = f2bf(v.x); s.y = f2bf(v.y); s.z = f2bf(v.z); s.w = f2bf(v.w);
                *(short4*)&A_l[tid * 40 + q * 4] = s;
            }
        }
        // stage B (transposed): 80 cols x 32 k. thread: kk=tid>>3, 10 cols each
        {
            int kk = tid >> 3;
            int c0 = (tid & 7) * 10;
            int kg = k0 + kk;
            #pragma unroll
            for (int c = 0; c < 10; ++c) {
                float v = (kg < DD) ? Wl[(size_t)kg * N4H + n0 + c0 + c] : 0.f;
                B_l[(c0 + c) * 40 + kk] = f2bf(v);
            }
        }
        __syncthreads();
        // fragments + MFMA. A[m=lane&15][k=quad*8+j], B[k=quad*8+j][n=lane&15]
        const int koff = (ln >> 4) * 8;
        bf16x8 afr[4], bfr[5];
        #pragma unroll
        for (int mt = 0; mt < 4; ++mt) {
            int row = wv * 64 + mt * 16 + (ln & 15);
            afr[mt] = *(const bf16x8*)&A_l[row * 40 + koff];
        }
        #pragma unroll
        for (int nt = 0; nt < 5; ++nt) {
            int col = nt * 16 + (ln & 15);
            bfr[nt] = *(const bf16x8*)&B_l[col * 40 + koff];
        }
        #pragma unroll
        for (int mt = 0; mt < 4; ++mt)
            #pragma unroll
            for (int nt = 0; nt < 5; ++nt)
                acc[mt][nt] = __builtin_amdgcn_mfma_f32_16x16x32_bf16(
                    afr[mt], bfr[nt], acc[mt][nt], 0, 0, 0);
    }
    // epilogue: C row=(lane>>4)*4+reg, col=lane&15; add bias
    #pragma unroll
    for (int mt = 0; mt < 4; ++mt) {
        #pragma unroll
        for (int nt = 0; nt < 5; ++nt) {
            #pragma unroll
            for (int rg = 0; rg < 4; ++rg) {
                int row = m0 + wv * 64 + mt * 16 + (ln >> 4) * 4 + rg;
                int col = n0 + nt * 16 + (ln & 15);
                zx[(size_t)row * N4H + col] = acc[mt][nt][rg] + bl[col];
            }
        }
    }
}

// ---------------------------------------------------------------------------
// Phase 2: persistent recurrent kernel. 240 WGs = 16 row-groups x 15 col-groups.
// Recurrent GEMM: F16 MFMA with h-side split (R8 post-mortem: 2x15 bf16 frag
// pinning = 240 VGPRs -> allocator spilled to scratch, 1.9 GB/dispatch HBM).
//   z = (h_hi + h_lo) @ W_f16,  h_hi = f16(h), h_lo = f16(h - h_hi)
// A-side error ~2^-23 (split), B-side ~2^-12 (f16 ulp). Measured bf16-both
// (2^-9) gave 7.7e-2 -> predicted ~5e-3 here, 4x under threshold.
// W_h: 15 pre-packed f16 B-fragments = 60 VGPRs/lane (R5/R6-proven pin
// regime), pinned by in-loop empty asm. M=16 (8 real + 8 pad rows), N=80,
// K split across waves; wave 3 has 288..299 real, rest zero.
// fp32 h state crosses WGs in the tagged words (no recurrent carry loss).
//
// NaN guard (R6): both h planes zeroed IN FULL once per dispatch, so wave 3's
// A reads of cols 300..319 are exact 0 (B=0 there; 0*0=0).
//
// Sync unchanged from R5: one-way tagged-word exchange, coalesced batched poll.
// Hazard closure: MFMA-read(t) < zp-barrier(t) < poll-write(t+1); post-poll
// barrier(t+1) separates gate zp-reads(t) from zp-writes(t+1).
// ---------------------------------------------------------------------------
__global__ __launch_bounds__(256, 1) void lstm_rec(
    const float* __restrict__ zx, const float* __restrict__ Wl,
    const int* __restrict__ lens, ull* __restrict__ ex,
    float* __restrict__ cst, float* __restrict__ hfin, int t0)
{
    const int tid = threadIdx.x;
    const int wv  = tid >> 6, ln = tid & 63;
    const int rg  = blockIdx.x % GR;
    const int cgi = blockIdx.x / GR;
    const int r0  = rg * RPW;
    const int u0  = cgi * UPW;
    const int m   = ln & 15;           // MFMA row / col-in-tile
    const int quad = ln >> 4;

    // ---- one-time: pack W_h f16 B-fragments for this wave's k-window ----
    // B[k=quad*8+j][n=lane&15]; frag f = s*5+nt covers kstep s, ntile nt.
    f16x8 bfr[15];
    #pragma unroll
    for (int s = 0; s < 3; ++s) {
        #pragma unroll
        for (int nt = 0; nt < 5; ++nt) {
            int c    = nt * 16 + m;            // 0..79 within WG cols
            int gate = c / 20;
            int wcol = 300 * gate + u0 + (c % 20);
            f16x8 b;
            #pragma unroll
            for (int j = 0; j < 8; ++j) {
                int k = KSW * wv + 32 * s + quad * 8 + j;
                float v = (k < HU) ? Wl[(size_t)(DD + k) * N4H + wcol] : 0.f;
                b[j] = (_Float16)v;
            }
            bfr[s * 5 + nt] = b;
        }
    }
    const int nks = (wv == 3) ? 1 : 3;   // wave 3: only kstep 0 has real k

    __shared__ short h_hi[HLB_SIZE];        // f16 hi plane of h_{t-1}
    __shared__ short h_lo[HLB_SIZE];        // f16 lo plane of h_{t-1}
    __shared__ float zp[4][RPW][84];        // per-wave k-partials (pad 80->84)

    // zero BOTH planes in full once per dispatch (NaN guard, see header)
    for (int i = tid; i < HLB_SIZE; i += 256) { h_hi[i] = 0; h_lo[i] = 0; }

    // gate role (tid < 160): u = tid%20, r = tid/20; c/h_old in registers
    const int g_u = tid % UPW, g_r = tid / UPW;
    const bool gl = (tid < RPW * UPW);
    float c_reg = 0.f, ho_reg = 0.f;
    int mylen = 0;
    if (gl) {
        c_reg = cst[(size_t)(r0 + g_r) * HU + u0 + g_u];
        mylen = lens[r0 + g_r];
        if (t0 > 0) {   // reload own h_{t0-1} (tag t0, parity t0&1) from last dispatch
            ull v = __hip_atomic_load(
                ex + (((size_t)(t0 & 1) * GR + rg) * RPW + g_r) * HU + u0 + g_u,
                __ATOMIC_RELAXED, __HIP_MEMORY_SCOPE_AGENT);
            ho_reg = __uint_as_float((unsigned)v);
        }
    }
    __syncthreads();   // zero-init visible before first poll writes

    for (int tc = 0; tc < CHUNK; ++tc) {
        const int t = t0 + tc;

        // pin B-fragments in VGPRs (empty asm: no insts, blocks remat/spill)
        #pragma unroll
        for (int f = 0; f < 15; ++f) {
            int4& q = *(int4*)&bfr[f];
            asm volatile("" : "+v"(q.x), "+v"(q.y), "+v"(q.z), "+v"(q.w));
        }

        // prefetch zx for this step (independent of h)
        float z_pre[4];
        if (gl) {
            const float* zrow = zx + ((size_t)(r0 + g_r) * CHUNK + tc) * N4H;
            #pragma unroll
            for (int gg = 0; gg < 4; ++gg)
                z_pre[gg] = zrow[300 * gg + u0 + g_u];
        }

        // ---- stage h_{t-1} hi/lo f16: coalesced batched tagged poll ----
        if (t == 0) {
            for (int i = tid; i < RPW * HU; i += 256) {
                int idx = (i / HU) * HLB_STRIDE + (i % HU);
                h_hi[idx] = 0; h_lo[idx] = 0;
            }
        } else {
            const ull* exb = ex + ((size_t)(t & 1) * GR + rg) * (RPW * HU);
            unsigned pend = (tid < (RPW * HU - 9 * 256)) ? 0x3FFu : 0x1FFu;
            do {
                ull v[10];
                #pragma unroll
                for (int k = 0; k < 10; ++k)
                    if ((pend >> k) & 1)
                        v[k] = __hip_atomic_load(exb + tid + (k << 8),
                                                 __ATOMIC_RELAXED,
                                                 __HIP_MEMORY_SCOPE_AGENT);
                unsigned got = 0;
                #pragma unroll
                for (int k = 0; k < 10; ++k) {
                    if (((pend >> k) & 1) && (int)(v[k] >> 32) >= t) {
                        int i = tid + (k << 8);
                        int idx = (i / HU) * HLB_STRIDE + (i % HU);
                        float f = __uint_as_float((unsigned)v[k]);
                        short hi = f2h(f);
                        h_hi[idx] = hi;
                        h_lo[idx] = f2h(f - h2f(hi));
                        got |= 1u << k;
                    }
                }
                pend &= ~got;
                if (pend) __builtin_amdgcn_s_sleep(1);
            } while (pend);
        }
        __syncthreads();

        // ---- MFMA: A hi/lo from LDS, B f16 from registers, 2 products ----
        f32x4 acc[5];
        #pragma unroll
        for (int nt = 0; nt < 5; ++nt) acc[nt] = (f32x4){0.f, 0.f, 0.f, 0.f};
        for (int s = 0; s < nks; ++s) {
            const int aoff = m * HLB_STRIDE + KSW * wv + 32 * s + quad * 8;
            f16x8 ah = *(const f16x8*)&h_hi[aoff];
            f16x8 al = *(const f16x8*)&h_lo[aoff];
            #pragma unroll
            for (int nt = 0; nt < 5; ++nt)
                acc[nt] = __builtin_amdgcn_mfma_f32_16x16x32_f16(
                    ah, bfr[s * 5 + nt], acc[nt], 0, 0, 0);
            #pragma unroll
            for (int nt = 0; nt < 5; ++nt)
                acc[nt] = __builtin_amdgcn_mfma_f32_16x16x32_f16(
                    al, bfr[s * 5 + nt], acc[nt], 0, 0, 0);
        }
        // C: row=quad*4+reg (lanes 0-31 -> rows 0-7), col=nt*16+m
        if (ln < 32) {
            #pragma unroll
            for (int nt = 0; nt < 5; ++nt)
                #pragma unroll
                for (int r4 = 0; r4 < 4; ++r4)
                    zp[wv][quad * 4 + r4][nt * 16 + m] = acc[nt][r4];
        }
        __syncthreads();

        // ---- reduce 4 partials + gates + tagged publish (160 threads) ----
        if (gl) {
            const int b = r0 + g_r;
            float z4[4];
            #pragma unroll
            for (int gg = 0; gg < 4; ++gg) {
                int cidx = gg * UPW + g_u;
                z4[gg] = z_pre[gg] + zp[0][g_r][cidx] + zp[1][g_r][cidx]
                                   + zp[2][g_r][cidx] + zp[3][g_r][cidx];
            }
            float ig = sigm(z4[0]);
            float jg = tanh_(z4[1]);
            float fg = sigm(z4[2] + 1.0f);   // FORGET_BIAS
            float og = sigm(z4[3]);
            float c_new = c_reg * fg + ig * jg;
            float h_new = tanh_(c_new) * og;
            bool upd = (t < mylen);
            ho_reg = upd ? h_new : ho_reg;
            c_reg  = upd ? c_new : c_reg;
            // publish h_t (tag t+1, parity (t+1)&1) — fire & forget
            ull pk = ((ull)(unsigned)(t + 1) << 32) | (ull)__float_as_uint(ho_reg);
            __hip_atomic_store(
                ex + (((size_t)((t + 1) & 1) * GR + rg) * RPW + g_r) * HU + u0 + g_u,
                pk, __ATOMIC_RELAXED, __HIP_MEMORY_SCOPE_AGENT);
            if (tc == CHUNK - 1) hfin[(size_t)b * HU + u0 + g_u] = ho_reg;
        }
        // no trailing barrier: poll-accept of t+1 requires own publish (self is
        // a producer), which orders all zp/h-plane reuse.
    }
    if (gl) cst[(size_t)(r0 + g_r) * HU + u0 + g_u] = c_reg;
}

// ---------------------------------------------------------------------------
// Phase 3: logits = h_final @ W_dense + b_dense; log-softmax NLL; mean loss.
// One wave per batch row.
// ---------------------------------------------------------------------------
__global__ __launch_bounds__(64) void cls_kernel(
    const float* __restrict__ hfin, const float* __restrict__ Wd,
    const float* __restrict__ bd, const int* __restrict__ labels,
    float* __restrict__ out)
{
    const int b = blockIdx.x;
    const int ln = threadIdx.x;
    const float* h = hfin + (size_t)b * HU;
    float p0 = 0.f, p1 = 0.f, p2 = 0.f;
    for (int k = ln; k < HU; k += 64) {
        float hv = h[k];
        p0 += hv * Wd[k * 3 + 0];
        p1 += hv * Wd[k * 3 + 1];
        p2 += hv * Wd[k * 3 + 2];
    }
    #pragma unroll
    for (int off = 32; off > 0; off >>= 1) {
        p0 += __shfl_down(p0, off);
        p1 += __shfl_down(p1, off);
        p2 += __shfl_down(p2, off);
    }
    if (ln == 0) {
        float l0 = p0 + bd[0], l1 = p1 + bd[1], l2 = p2 + bd[2];
        float m = fmaxf(l0, fmaxf(l1, l2));
        float lse = m + logf(__expf(l0 - m) + __expf(l1 - m) + __expf(l2 - m));
        int lab = labels[b];
        float sel = (lab == 0) ? l0 : ((lab == 1) ? l1 : l2);
        float nll = lse - sel;
        out[1 + b * 3 + 0] = l0;
        out[1 + b * 3 + 1] = l1;
        out[1 + b * 3 + 2] = l2;
        atomicAdd(out, nll * (1.0f / BB));
    }
}

// ---------------------------------------------------------------------------
extern "C" void kernel_launch(void* const* d_in, const int* in_sizes, int n_in,
                              void* d_out, int out_size, void* d_ws, size_t ws_size,
                              hipStream_t stream) {
    const int*   ids  = (const int*)d_in[0];
    const int*   lens = (const int*)d_in[1];
    const int*   labs = (const int*)d_in[2];
    const float* emb  = (const float*)d_in[3];
    const float* Wl   = (const float*)d_in[4];
    const float* bl   = (const float*)d_in[5];
    const float* Wd   = (const float*)d_in[6];
    const float* bd   = (const float*)d_in[7];
    float* out = (float*)d_out;

    float* zx   = (float*)d_ws;
    ull*   ex   = (ull*)(zx + ZX_F);
    float* cst  = (float*)(ex + EX_W);
    float* hfin = cst + CST_F;

    {   // zero exchange tags / c state / out[0]
        int n = (int)((EX_W + 255) / 256);
        init_kernel<<<n, 256, 0, stream>>>(ex, cst, out);
    }
    for (int c = 0; c < NCHUNK; ++c) {
        int t0 = c * CHUNK;
        zx_gemm<<<dim3(32, 15), 256, 0, stream>>>(emb, ids, Wl, bl, zx, t0);
        lstm_rec<<<GR * GC, 256, 0, stream>>>(zx, Wl, lens, ex, cst, hfin, t0);
    }
    cls_kernel<<<BB, 64, 0, stream>>>(hfin, Wd, bd, labs, out);
}

// Round 10
// 2667.501 us; speedup vs baseline: 2.5951x; 1.5293x over previous
//
#include <hip/hip_runtime.h>
#include <hip/hip_bf16.h>
#include <math.h>

// Problem constants
#define VV   32000
#define DD   300
#define HU   300
#define NC   3
#define BB   128
#define TT   512
#define N4H  1200
#define CHUNK 64
#define NCHUNK (TT / CHUNK)

// Recurrent kernel partition
#define GC   15   // col groups (units)
#define GR   16   // row groups
#define RPW  8    // rows per WG (BB/GR)
#define UPW  20   // units per WG (HU/GC)
#define KSW  96   // k-window per wave (4 waves x 96 covers 300 w/ zero pad)
#define HLB_STRIDE 312            // h plane row stride in shorts (624B: 16B-aligned, 2-way bank alias = free)
#define HLB_SIZE   (16 * HLB_STRIDE + 32)

// Workspace layout: [zx (float)][ex (ulong, tagged h exchange)][cst][hfin]
static constexpr size_t ZX_F   = (size_t)BB * CHUNK * N4H;   // 9,830,400 floats
static constexpr size_t EX_W   = (size_t)2 * GR * RPW * HU;  // 76,800 ulongs
static constexpr size_t CST_F  = (size_t)BB * HU;            // 38,400 floats
static constexpr size_t HFIN_F = (size_t)BB * HU;            // 38,400 floats

typedef __attribute__((ext_vector_type(8))) short bf16x8;
typedef __attribute__((ext_vector_type(8))) _Float16 f16x8;
typedef __attribute__((ext_vector_type(4))) float f32x4;
typedef unsigned long long ull;

__device__ __forceinline__ short f2bf(float f) {
    unsigned u = __float_as_uint(f);
    u += 0x7fff + ((u >> 16) & 1);   // round-to-nearest-even
    return (short)(u >> 16);
}
__device__ __forceinline__ short f2h(float f) {   // float -> f16 bits (RTNE)
    _Float16 h = (_Float16)f;
    return *(short*)&h;
}
__device__ __forceinline__ float h2f(short s) {
    _Float16 h = *(_Float16*)&s;
    return (float)h;
}
__device__ __forceinline__ float sigm(float x) { return 1.f / (1.f + __expf(-x)); }
__device__ __forceinline__ float tanh_(float x) { return 1.f - 2.f / (__expf(2.f * x) + 1.f); }

// ---------------------------------------------------------------------------
// init: zero exchange tags, c state, out[0]  (ws is poisoned 0xAA every launch)
// ---------------------------------------------------------------------------
__global__ void init_kernel(ull* __restrict__ ex, float* __restrict__ cst,
                            float* __restrict__ out) {
    size_t i = (size_t)blockIdx.x * 256 + threadIdx.x;
    if (i < EX_W) ex[i] = 0ull;
    if (i < CST_F) cst[i] = 0.f;
    if (i == 0) out[0] = 0.f;
}

// ---------------------------------------------------------------------------
// Phase 1: zx[b][tc][n] = emb[ids[b][t0+tc]] @ W_lstm[0:300] + b_lstm   (bf16 MFMA)
// WG tile: M=256 rows, N=80 cols, K=320 (300 zero-padded). 4 waves, wave = 64x80.
// grid = (8192/256, 1200/80) = (32, 15)
// ---------------------------------------------------------------------------
__global__ __launch_bounds__(256) void zx_gemm(
    const float* __restrict__ emb, const int* __restrict__ ids,
    const float* __restrict__ Wl, const float* __restrict__ bl,
    float* __restrict__ zx, int t0)
{
    __shared__ short A_l[256 * 40];   // [row][k] pad 32->40 shorts
    __shared__ short B_l[80 * 40];    // [col][k] (transposed)
    __shared__ int   ids_l[256];

    const int tid = threadIdx.x;
    const int m0  = blockIdx.x * 256;
    const int n0  = blockIdx.y * 80;
    const int wv  = tid >> 6, ln = tid & 63;

    {   // per-row embedding id
        int m = m0 + tid;
        int b = m >> 6, tc = m & (CHUNK - 1);
        ids_l[tid] = ids[b * TT + t0 + tc];
    }

    f32x4 acc[4][5];
    for (int i = 0; i < 4; ++i)
        for (int j = 0; j < 5; ++j)
            acc[i][j] = (f32x4){0.f, 0.f, 0.f, 0.f};

    for (int k0 = 0; k0 < 320; k0 += 32) {
        __syncthreads();
        // stage A: 256 rows x 32 k, one row per thread (float4 x8, guard k<300)
        {
            const float* src = emb + (size_t)ids_l[tid] * DD;
            #pragma unroll
            for (int q = 0; q < 8; ++q) {
                int kg = k0 + q * 4;
                float4 v;
                if (kg < DD) v = *(const float4*)(src + kg);
                else         v = make_float4(0.f, 0.f, 0.f, 0.f);
                short4 s; s.x = f2bf(v.x); s.y = f2bf(v.y); s.z = f2bf(v.z); s.w = f2bf(v.w);
                *(short4*)&A_l[tid * 40 + q * 4] = s;
            }
        }
        // stage B (transposed): 80 cols x 32 k. thread: kk=tid>>3, 10 cols each
        {
            int kk = tid >> 3;
            int c0 = (tid & 7) * 10;
            int kg = k0 + kk;
            #pragma unroll
            for (int c = 0; c < 10; ++c) {
                float v = (kg < DD) ? Wl[(size_t)kg * N4H + n0 + c0 + c] : 0.f;
                B_l[(c0 + c) * 40 + kk] = f2bf(v);
            }
        }
        __syncthreads();
        // fragments + MFMA. A[m=lane&15][k=quad*8+j], B[k=quad*8+j][n=lane&15]
        const int koff = (ln >> 4) * 8;
        bf16x8 afr[4], bfr[5];
        #pragma unroll
        for (int mt = 0; mt < 4; ++mt) {
            int row = wv * 64 + mt * 16 + (ln & 15);
            afr[mt] = *(const bf16x8*)&A_l[row * 40 + koff];
        }
        #pragma unroll
        for (int nt = 0; nt < 5; ++nt) {
            int col = nt * 16 + (ln & 15);
            bfr[nt] = *(const bf16x8*)&B_l[col * 40 + koff];
        }
        #pragma unroll
        for (int mt = 0; mt < 4; ++mt)
            #pragma unroll
            for (int nt = 0; nt < 5; ++nt)
                acc[mt][nt] = __builtin_amdgcn_mfma_f32_16x16x32_bf16(
                    afr[mt], bfr[nt], acc[mt][nt], 0, 0, 0);
    }
    // epilogue: C row=(lane>>4)*4+reg, col=lane&15; add bias
    #pragma unroll
    for (int mt = 0; mt < 4; ++mt) {
        #pragma unroll
        for (int nt = 0; nt < 5; ++nt) {
            #pragma unroll
            for (int rg = 0; rg < 4; ++rg) {
                int row = m0 + wv * 64 + mt * 16 + (ln >> 4) * 4 + rg;
                int col = n0 + nt * 16 + (ln & 15);
                zx[(size_t)row * N4H + col] = acc[mt][nt][rg] + bl[col];
            }
        }
    }
}

// ---------------------------------------------------------------------------
// Phase 2: persistent recurrent kernel. 240 WGs = 16 row-groups x 15 col-groups.
// Recurrent GEMM: F16 MFMA with h-side split:
//   z = (h_hi + h_lo) @ W_f16,  h_hi = f16(h), h_lo = f16(h - h_hi)
// A-side error ~2^-23, B-side ~2^-12. Measured: same absmax (4.88e-4 floor)
// as the fp32-GEMM R5 kernel.
//
// R9 post-mortem: register-resident W fragments (60 VGPRs) + pin asm =
// allocator spills part of the array to scratch, and the in-loop pin forces
// a scratch round-trip EVERY step (WRITE_SIZE 235 MB/dispatch). Fix: W_h
// fragments live in LDS, packed in MFMA fragment order (w_l[wv][frag][lane],
// 16 B/lane contiguous -> ds_read_b128, 2-way bank alias = free). 60 KB LDS,
// total ~91 KB/WG -> still 1 WG/CU, which 240 WGs need anyway. No pin asm,
// no spill possible; per step cost = 15 ds_read_b128/wave (~180 cyc issue).
//
// NaN guard (R6): both h planes zeroed IN FULL once per dispatch, so wave 3's
// A reads of cols 300..319 are exact 0 (B=0 there; 0*0=0).
//
// Sync unchanged from R5: one-way tagged-word exchange (tag<<32|f32),
// relaxed agent-scope atomics, coalesced batched poll.
// Hazard closure: MFMA-read(t) < zp-barrier(t) < poll-write(t+1); post-poll
// barrier(t+1) separates gate zp-reads(t) from zp-writes(t+1).
// ---------------------------------------------------------------------------
__global__ __launch_bounds__(256, 1) void lstm_rec(
    const float* __restrict__ zx, const float* __restrict__ Wl,
    const int* __restrict__ lens, ull* __restrict__ ex,
    float* __restrict__ cst, float* __restrict__ hfin, int t0)
{
    const int tid = threadIdx.x;
    const int wv  = tid >> 6, ln = tid & 63;
    const int rg  = blockIdx.x % GR;
    const int cgi = blockIdx.x / GR;
    const int r0  = rg * RPW;
    const int u0  = cgi * UPW;
    const int m   = ln & 15;           // MFMA row / col-in-tile
    const int quad = ln >> 4;

    __shared__ short h_hi[HLB_SIZE];        // f16 hi plane of h_{t-1}
    __shared__ short h_lo[HLB_SIZE];        // f16 lo plane of h_{t-1}
    __shared__ float zp[4][RPW][84];        // per-wave k-partials (pad 80->84)
    __shared__ short w_l[4 * 15 * 64 * 8];  // f16 W_h fragments, frag-ordered

    // ---- one-time: pack W_h f16 B-fragments into LDS ----
    // B[k=quad*8+j][n=lane&15]; frag f = s*5+nt covers kstep s, ntile nt.
    #pragma unroll
    for (int s = 0; s < 3; ++s) {
        #pragma unroll
        for (int nt = 0; nt < 5; ++nt) {
            int c    = nt * 16 + m;            // 0..79 within WG cols
            int gate = c / 20;
            int wcol = 300 * gate + u0 + (c % 20);
            f16x8 b;
            #pragma unroll
            for (int j = 0; j < 8; ++j) {
                int k = KSW * wv + 32 * s + quad * 8 + j;
                float v = (k < HU) ? Wl[(size_t)(DD + k) * N4H + wcol] : 0.f;
                b[j] = (_Float16)v;
            }
            *(f16x8*)&w_l[(((wv * 15) + (s * 5 + nt)) * 64 + ln) * 8] = b;
        }
    }
    const int nks = (wv == 3) ? 1 : 3;   // wave 3: only kstep 0 has real k

    // zero BOTH h planes in full once per dispatch (NaN guard, see header)
    for (int i = tid; i < HLB_SIZE; i += 256) { h_hi[i] = 0; h_lo[i] = 0; }

    // gate role (tid < 160): u = tid%20, r = tid/20; c/h_old in registers
    const int g_u = tid % UPW, g_r = tid / UPW;
    const bool gl = (tid < RPW * UPW);
    float c_reg = 0.f, ho_reg = 0.f;
    int mylen = 0;
    if (gl) {
        c_reg = cst[(size_t)(r0 + g_r) * HU + u0 + g_u];
        mylen = lens[r0 + g_r];
        if (t0 > 0) {   // reload own h_{t0-1} (tag t0, parity t0&1) from last dispatch
            ull v = __hip_atomic_load(
                ex + (((size_t)(t0 & 1) * GR + rg) * RPW + g_r) * HU + u0 + g_u,
                __ATOMIC_RELAXED, __HIP_MEMORY_SCOPE_AGENT);
            ho_reg = __uint_as_float((unsigned)v);
        }
    }
    __syncthreads();   // w_l pack + zero-init visible before first step

    for (int tc = 0; tc < CHUNK; ++tc) {
        const int t = t0 + tc;

        // prefetch zx for this step (independent of h)
        float z_pre[4];
        if (gl) {
            const float* zrow = zx + ((size_t)(r0 + g_r) * CHUNK + tc) * N4H;
            #pragma unroll
            for (int gg = 0; gg < 4; ++gg)
                z_pre[gg] = zrow[300 * gg + u0 + g_u];
        }

        // ---- stage h_{t-1} hi/lo f16: coalesced batched tagged poll ----
        if (t == 0) {
            for (int i = tid; i < RPW * HU; i += 256) {
                int idx = (i / HU) * HLB_STRIDE + (i % HU);
                h_hi[idx] = 0; h_lo[idx] = 0;
            }
        } else {
            const ull* exb = ex + ((size_t)(t & 1) * GR + rg) * (RPW * HU);
            unsigned pend = (tid < (RPW * HU - 9 * 256)) ? 0x3FFu : 0x1FFu;
            do {
                ull v[10];
                #pragma unroll
                for (int k = 0; k < 10; ++k)
                    if ((pend >> k) & 1)
                        v[k] = __hip_atomic_load(exb + tid + (k << 8),
                                                 __ATOMIC_RELAXED,
                                                 __HIP_MEMORY_SCOPE_AGENT);
                unsigned got = 0;
                #pragma unroll
                for (int k = 0; k < 10; ++k) {
                    if (((pend >> k) & 1) && (int)(v[k] >> 32) >= t) {
                        int i = tid + (k << 8);
                        int idx = (i / HU) * HLB_STRIDE + (i % HU);
                        float f = __uint_as_float((unsigned)v[k]);
                        short hi = f2h(f);
                        h_hi[idx] = hi;
                        h_lo[idx] = f2h(f - h2f(hi));
                        got |= 1u << k;
                    }
                }
                pend &= ~got;
                if (pend) __builtin_amdgcn_s_sleep(1);
            } while (pend);
        }
        __syncthreads();

        // ---- MFMA: A hi/lo from LDS, B f16 from LDS (fragment-ordered) ----
        f32x4 acc[5];
        #pragma unroll
        for (int nt = 0; nt < 5; ++nt) acc[nt] = (f32x4){0.f, 0.f, 0.f, 0.f};
        for (int s = 0; s < nks; ++s) {
            const int aoff = m * HLB_STRIDE + KSW * wv + 32 * s + quad * 8;
            f16x8 ah = *(const f16x8*)&h_hi[aoff];
            f16x8 al = *(const f16x8*)&h_lo[aoff];
            f16x8 bfr[5];
            #pragma unroll
            for (int nt = 0; nt < 5; ++nt)
                bfr[nt] = *(const f16x8*)&w_l[(((wv * 15) + (s * 5 + nt)) * 64 + ln) * 8];
            #pragma unroll
            for (int nt = 0; nt < 5; ++nt)
                acc[nt] = __builtin_amdgcn_mfma_f32_16x16x32_f16(
                    ah, bfr[nt], acc[nt], 0, 0, 0);
            #pragma unroll
            for (int nt = 0; nt < 5; ++nt)
                acc[nt] = __builtin_amdgcn_mfma_f32_16x16x32_f16(
                    al, bfr[nt], acc[nt], 0, 0, 0);
        }
        // C: row=quad*4+reg (lanes 0-31 -> rows 0-7), col=nt*16+m
        if (ln < 32) {
            #pragma unroll
            for (int nt = 0; nt < 5; ++nt)
                #pragma unroll
                for (int r4 = 0; r4 < 4; ++r4)
                    zp[wv][quad * 4 + r4][nt * 16 + m] = acc[nt][r4];
        }
        __syncthreads();

        // ---- reduce 4 partials + gates + tagged publish (160 threads) ----
        if (gl) {
            const int b = r0 + g_r;
            float z4[4];
            #pragma unroll
            for (int gg = 0; gg < 4; ++gg) {
                int cidx = gg * UPW + g_u;
                z4[gg] = z_pre[gg] + zp[0][g_r][cidx] + zp[1][g_r][cidx]
                                   + zp[2][g_r][cidx] + zp[3][g_r][cidx];
            }
            float ig = sigm(z4[0]);
            float jg = tanh_(z4[1]);
            float fg = sigm(z4[2] + 1.0f);   // FORGET_BIAS
            float og = sigm(z4[3]);
            float c_new = c_reg * fg + ig * jg;
            float h_new = tanh_(c_new) * og;
            bool upd = (t < mylen);
            ho_reg = upd ? h_new : ho_reg;
            c_reg  = upd ? c_new : c_reg;
            // publish h_t (tag t+1, parity (t+1)&1) — fire & forget
            ull pk = ((ull)(unsigned)(t + 1) << 32) | (ull)__float_as_uint(ho_reg);
            __hip_atomic_store(
                ex + (((size_t)((t + 1) & 1) * GR + rg) * RPW + g_r) * HU + u0 + g_u,
                pk, __ATOMIC_RELAXED, __HIP_MEMORY_SCOPE_AGENT);
            if (tc == CHUNK - 1) hfin[(size_t)b * HU + u0 + g_u] = ho_reg;
        }
        // no trailing barrier: poll-accept of t+1 requires own publish (self is
        // a producer), which orders all zp/h-plane reuse.
    }
    if (gl) cst[(size_t)(r0 + g_r) * HU + u0 + g_u] = c_reg;
}

// ---------------------------------------------------------------------------
// Phase 3: logits = h_final @ W_dense + b_dense; log-softmax NLL; mean loss.
// One wave per batch row.
// ---------------------------------------------------------------------------
__global__ __launch_bounds__(64) void cls_kernel(
    const float* __restrict__ hfin, const float* __restrict__ Wd,
    const float* __restrict__ bd, const int* __restrict__ labels,
    float* __restrict__ out)
{
    const int b = blockIdx.x;
    const int ln = threadIdx.x;
    const float* h = hfin + (size_t)b * HU;
    float p0 = 0.f, p1 = 0.f, p2 = 0.f;
    for (int k = ln; k < HU; k += 64) {
        float hv = h[k];
        p0 += hv * Wd[k * 3 + 0];
        p1 += hv * Wd[k * 3 + 1];
        p2 += hv * Wd[k * 3 + 2];
    }
    #pragma unroll
    for (int off = 32; off > 0; off >>= 1) {
        p0 += __shfl_down(p0, off);
        p1 += __shfl_down(p1, off);
        p2 += __shfl_down(p2, off);
    }
    if (ln == 0) {
        float l0 = p0 + bd[0], l1 = p1 + bd[1], l2 = p2 + bd[2];
        float m = fmaxf(l0, fmaxf(l1, l2));
        float lse = m + logf(__expf(l0 - m) + __expf(l1 - m) + __expf(l2 - m));
        int lab = labels[b];
        float sel = (lab == 0) ? l0 : ((lab == 1) ? l1 : l2);
        float nll = lse - sel;
        out[1 + b * 3 + 0] = l0;
        out[1 + b * 3 + 1] = l1;
        out[1 + b * 3 + 2] = l2;
        atomicAdd(out, nll * (1.0f / BB));
    }
}

// ---------------------------------------------------------------------------
extern "C" void kernel_launch(void* const* d_in, const int* in_sizes, int n_in,
                              void* d_out, int out_size, void* d_ws, size_t ws_size,
                              hipStream_t stream) {
    const int*   ids  = (const int*)d_in[0];
    const int*   lens = (const int*)d_in[1];
    const int*   labs = (const int*)d_in[2];
    const float* emb  = (const float*)d_in[3];
    const float* Wl   = (const float*)d_in[4];
    const float* bl   = (const float*)d_in[5];
    const float* Wd   = (const float*)d_in[6];
    const float* bd   = (const float*)d_in[7];
    float* out = (float*)d_out;

    float* zx   = (float*)d_ws;
    ull*   ex   = (ull*)(zx + ZX_F);
    float* cst  = (float*)(ex + EX_W);
    float* hfin = cst + CST_F;

    {   // zero exchange tags / c state / out[0]
        int n = (int)((EX_W + 255) / 256);
        init_kernel<<<n, 256, 0, stream>>>(ex, cst, out);
    }
    for (int c = 0; c < NCHUNK; ++c) {
        int t0 = c * CHUNK;
        zx_gemm<<<dim3(32, 15), 256, 0, stream>>>(emb, ids, Wl, bl, zx, t0);
        lstm_rec<<<GR * GC, 256, 0, stream>>>(zx, Wl, lens, ex, cst, hfin, t0);
    }
    cls_kernel<<<BB, 64, 0, stream>>>(hfin, Wd, bd, labs, out);
}

// Round 11
// 2605.008 us; speedup vs baseline: 2.6573x; 1.0240x over previous
//
#include <hip/hip_runtime.h>
#include <hip/hip_bf16.h>
#include <math.h>

// Problem constants
#define VV   32000
#define DD   300
#define HU   300
#define NC   3
#define BB   128
#define TT   512
#define N4H  1200
#define CHUNK 64
#define NCHUNK (TT / CHUNK)

// Recurrent kernel partition
#define GC   15   // col groups (units)
#define GR   16   // row groups
#define RPW  8    // rows per WG (BB/GR)
#define UPW  20   // units per WG (HU/GC)
#define KSW  96   // k-window per wave (4 waves x 96 covers 300 w/ zero pad)
#define HLB_STRIDE 312            // h plane row stride in shorts (624B: 16B-aligned, 2-way bank alias = free)
#define HLB_SIZE   (16 * HLB_STRIDE + 32)

// Workspace layout: [zx (float)][ex (ulong, tagged h exchange)][cst][hfin]
static constexpr size_t ZX_F   = (size_t)BB * CHUNK * N4H;   // 9,830,400 floats
static constexpr size_t EX_W   = (size_t)2 * GR * RPW * HU;  // 76,800 ulongs
static constexpr size_t CST_F  = (size_t)BB * HU;            // 38,400 floats
static constexpr size_t HFIN_F = (size_t)BB * HU;            // 38,400 floats

typedef __attribute__((ext_vector_type(8))) short bf16x8;
typedef __attribute__((ext_vector_type(8))) _Float16 f16x8;
typedef __attribute__((ext_vector_type(4))) float f32x4;
typedef unsigned long long ull;

__device__ __forceinline__ short f2bf(float f) {
    unsigned u = __float_as_uint(f);
    u += 0x7fff + ((u >> 16) & 1);   // round-to-nearest-even
    return (short)(u >> 16);
}
__device__ __forceinline__ short f2h(float f) {   // float -> f16 bits (RTNE)
    _Float16 h = (_Float16)f;
    return *(short*)&h;
}
__device__ __forceinline__ float h2f(short s) {
    _Float16 h = *(_Float16*)&s;
    return (float)h;
}
__device__ __forceinline__ float sigm(float x) { return 1.f / (1.f + __expf(-x)); }
__device__ __forceinline__ float tanh_(float x) { return 1.f - 2.f / (__expf(2.f * x) + 1.f); }

// ---------------------------------------------------------------------------
// init: zero exchange tags, c state, out[0]  (ws is poisoned 0xAA every launch)
// ---------------------------------------------------------------------------
__global__ void init_kernel(ull* __restrict__ ex, float* __restrict__ cst,
                            float* __restrict__ out) {
    size_t i = (size_t)blockIdx.x * 256 + threadIdx.x;
    if (i < EX_W) ex[i] = 0ull;
    if (i < CST_F) cst[i] = 0.f;
    if (i == 0) out[0] = 0.f;
}

// ---------------------------------------------------------------------------
// Phase 1: zx[b][tc][n] = emb[ids[b][t0+tc]] @ W_lstm[0:300] + b_lstm   (bf16 MFMA)
// WG tile: M=256 rows, N=80 cols, K=320 (300 zero-padded). 4 waves, wave = 64x80.
// grid = (8192/256, 1200/80) = (32, 15)
// ---------------------------------------------------------------------------
__global__ __launch_bounds__(256) void zx_gemm(
    const float* __restrict__ emb, const int* __restrict__ ids,
    const float* __restrict__ Wl, const float* __restrict__ bl,
    float* __restrict__ zx, int t0)
{
    __shared__ short A_l[256 * 40];   // [row][k] pad 32->40 shorts
    __shared__ short B_l[80 * 40];    // [col][k] (transposed)
    __shared__ int   ids_l[256];

    const int tid = threadIdx.x;
    const int m0  = blockIdx.x * 256;
    const int n0  = blockIdx.y * 80;
    const int wv  = tid >> 6, ln = tid & 63;

    {   // per-row embedding id
        int m = m0 + tid;
        int b = m >> 6, tc = m & (CHUNK - 1);
        ids_l[tid] = ids[b * TT + t0 + tc];
    }

    f32x4 acc[4][5];
    for (int i = 0; i < 4; ++i)
        for (int j = 0; j < 5; ++j)
            acc[i][j] = (f32x4){0.f, 0.f, 0.f, 0.f};

    for (int k0 = 0; k0 < 320; k0 += 32) {
        __syncthreads();
        // stage A: 256 rows x 32 k, one row per thread (float4 x8, guard k<300)
        {
            const float* src = emb + (size_t)ids_l[tid] * DD;
            #pragma unroll
            for (int q = 0; q < 8; ++q) {
                int kg = k0 + q * 4;
                float4 v;
                if (kg < DD) v = *(const float4*)(src + kg);
                else         v = make_float4(0.f, 0.f, 0.f, 0.f);
                short4 s; s.x = f2bf(v.x); s.y = f2bf(v.y); s.z = f2bf(v.z); s.w = f2bf(v.w);
                *(short4*)&A_l[tid * 40 + q * 4] = s;
            }
        }
        // stage B (transposed): 80 cols x 32 k. thread: kk=tid>>3, 10 cols each
        {
            int kk = tid >> 3;
            int c0 = (tid & 7) * 10;
            int kg = k0 + kk;
            #pragma unroll
            for (int c = 0; c < 10; ++c) {
                float v = (kg < DD) ? Wl[(size_t)kg * N4H + n0 + c0 + c] : 0.f;
                B_l[(c0 + c) * 40 + kk] = f2bf(v);
            }
        }
        __syncthreads();
        // fragments + MFMA. A[m=lane&15][k=quad*8+j], B[k=quad*8+j][n=lane&15]
        const int koff = (ln >> 4) * 8;
        bf16x8 afr[4], bfr[5];
        #pragma unroll
        for (int mt = 0; mt < 4; ++mt) {
            int row = wv * 64 + mt * 16 + (ln & 15);
            afr[mt] = *(const bf16x8*)&A_l[row * 40 + koff];
        }
        #pragma unroll
        for (int nt = 0; nt < 5; ++nt) {
            int col = nt * 16 + (ln & 15);
            bfr[nt] = *(const bf16x8*)&B_l[col * 40 + koff];
        }
        #pragma unroll
        for (int mt = 0; mt < 4; ++mt)
            #pragma unroll
            for (int nt = 0; nt < 5; ++nt)
                acc[mt][nt] = __builtin_amdgcn_mfma_f32_16x16x32_bf16(
                    afr[mt], bfr[nt], acc[mt][nt], 0, 0, 0);
    }
    // epilogue: C row=(lane>>4)*4+reg, col=lane&15; add bias
    #pragma unroll
    for (int mt = 0; mt < 4; ++mt) {
        #pragma unroll
        for (int nt = 0; nt < 5; ++nt) {
            #pragma unroll
            for (int rg = 0; rg < 4; ++rg) {
                int row = m0 + wv * 64 + mt * 16 + (ln >> 4) * 4 + rg;
                int col = n0 + nt * 16 + (ln & 15);
                zx[(size_t)row * N4H + col] = acc[mt][nt][rg] + bl[col];
            }
        }
    }
}

// ---------------------------------------------------------------------------
// Phase 2: persistent recurrent kernel. 240 WGs = 16 row-groups x 15 col-groups.
// Recurrent GEMM: F16 MFMA with h-side split (absmax at 4.88e-4 output floor):
//   z = (h_hi + h_lo) @ W_f16,  h_hi = f16(h), h_lo = f16(h - h_hi)
// W_h f16 fragments live in LDS, fragment-ordered (R10: no VGPR spill).
//
// R11: PER-WAVE K-WINDOW WAITING + single barrier per step.
//  - wave w's MFMA reads only h cols [96w, 96w+96) -> wave w polls exactly
//    that stripe (768 words = 12/lane; wave 3: 96 words) and proceeds to
//    MFMA with NO barrier. Fan-in per wait: ~5 producers instead of 15.
//  - zp is parity-double-buffered -> only ONE __syncthreads per step
//    (zp-write -> gate-read). zp[par] overwrite at t+2 is ordered after
//    barrier(t+1), which follows gate reads of zp[par] at t.
//  - tag-ABA safety (transitive, per-wave): publish(s+2) > barrier(s+1) >
//    all 4 waves detected tags s+1 over window-union = ALL 15 producers'
//    s+1 publishes >= every consumer's step-s reads (publish follows reads
//    in each consumer's program order).
//  - t==0 staging: none needed — one-time full zero of both planes is h0=0.
//
// NaN guard (R6): both h planes zeroed IN FULL once per dispatch, so wave 3's
// A reads of cols 300..319 are exact 0 (B=0 there; 0*0=0).
// ---------------------------------------------------------------------------
__global__ __launch_bounds__(256, 1) void lstm_rec(
    const float* __restrict__ zx, const float* __restrict__ Wl,
    const int* __restrict__ lens, ull* __restrict__ ex,
    float* __restrict__ cst, float* __restrict__ hfin, int t0)
{
    const int tid = threadIdx.x;
    const int wv  = tid >> 6, ln = tid & 63;
    const int rg  = blockIdx.x % GR;
    const int cgi = blockIdx.x / GR;
    const int r0  = rg * RPW;
    const int u0  = cgi * UPW;
    const int m   = ln & 15;           // MFMA row / col-in-tile
    const int quad = ln >> 4;

    __shared__ short h_hi[HLB_SIZE];        // f16 hi plane of h_{t-1}
    __shared__ short h_lo[HLB_SIZE];        // f16 lo plane of h_{t-1}
    __shared__ float zp[2][4][RPW][84];     // parity x wave k-partials (pad 80->84)
    __shared__ short w_l[4 * 15 * 64 * 8];  // f16 W_h fragments, frag-ordered

    // ---- one-time: pack W_h f16 B-fragments into LDS ----
    // B[k=quad*8+j][n=lane&15]; frag f = s*5+nt covers kstep s, ntile nt.
    #pragma unroll
    for (int s = 0; s < 3; ++s) {
        #pragma unroll
        for (int nt = 0; nt < 5; ++nt) {
            int c    = nt * 16 + m;            // 0..79 within WG cols
            int gate = c / 20;
            int wcol = 300 * gate + u0 + (c % 20);
            f16x8 b;
            #pragma unroll
            for (int j = 0; j < 8; ++j) {
                int k = KSW * wv + 32 * s + quad * 8 + j;
                float v = (k < HU) ? Wl[(size_t)(DD + k) * N4H + wcol] : 0.f;
                b[j] = (_Float16)v;
            }
            *(f16x8*)&w_l[(((wv * 15) + (s * 5 + nt)) * 64 + ln) * 8] = b;
        }
    }
    const int nks = (wv == 3) ? 1 : 3;   // wave 3: only kstep 0 has real k

    // zero BOTH h planes in full once per dispatch (NaN guard + h0 = 0)
    for (int i = tid; i < HLB_SIZE; i += 256) { h_hi[i] = 0; h_lo[i] = 0; }

    // gate role (tid < 160): u = tid%20, r = tid/20; c/h_old in registers
    const int g_u = tid % UPW, g_r = tid / UPW;
    const bool gl = (tid < RPW * UPW);
    float c_reg = 0.f, ho_reg = 0.f;
    int mylen = 0;
    if (gl) {
        c_reg = cst[(size_t)(r0 + g_r) * HU + u0 + g_u];
        mylen = lens[r0 + g_r];
        if (t0 > 0) {   // reload own h_{t0-1} (tag t0, parity t0&1) from last dispatch
            ull v = __hip_atomic_load(
                ex + (((size_t)(t0 & 1) * GR + rg) * RPW + g_r) * HU + u0 + g_u,
                __ATOMIC_RELAXED, __HIP_MEMORY_SCOPE_AGENT);
            ho_reg = __uint_as_float((unsigned)v);
        }
    }
    __syncthreads();   // h-plane zero + w_l pack visible before first step

    for (int tc = 0; tc < CHUNK; ++tc) {
        const int t = t0 + tc;
        const int par = t & 1;

        // prefetch zx for this step (independent of h)
        float z_pre[4];
        if (gl) {
            const float* zrow = zx + ((size_t)(r0 + g_r) * CHUNK + tc) * N4H;
            #pragma unroll
            for (int gg = 0; gg < 4; ++gg)
                z_pre[gg] = zrow[300 * gg + u0 + g_u];
        }

        // ---- per-wave stage of OWN K-window stripe (no barrier after) ----
        if (t > 0) {
            const ull* exb = ex + ((size_t)par * GR + rg) * (RPW * HU);
            if (wv < 3) {
                // 768 words: i = ln + 64k, r = i/96, u = 96*wv + i%96
                unsigned pend = 0xFFFu;
                do {
                    ull v[12];
                    #pragma unroll
                    for (int k = 0; k < 12; ++k)
                        if ((pend >> k) & 1) {
                            int i = ln + (k << 6);
                            int r = i / 96, u = KSW * wv + (i % 96);
                            v[k] = __hip_atomic_load(exb + r * HU + u,
                                                     __ATOMIC_RELAXED,
                                                     __HIP_MEMORY_SCOPE_AGENT);
                        }
                    unsigned got = 0;
                    #pragma unroll
                    for (int k = 0; k < 12; ++k) {
                        if (((pend >> k) & 1) && (int)(v[k] >> 32) >= t) {
                            int i = ln + (k << 6);
                            int r = i / 96, u = KSW * wv + (i % 96);
                            int idx = r * HLB_STRIDE + u;
                            float f = __uint_as_float((unsigned)v[k]);
                            short hi = f2h(f);
                            h_hi[idx] = hi;
                            h_lo[idx] = f2h(f - h2f(hi));
                            got |= 1u << k;
                        }
                    }
                    pend &= ~got;
                    if (pend) __builtin_amdgcn_s_sleep(1);
                } while (pend);
            } else {
                // 96 words: i = ln + 64k (i<96), r = i/12, u = 288 + i%12
                unsigned pend = (ln < 32) ? 0x3u : 0x1u;
                do {
                    ull v[2];
                    #pragma unroll
                    for (int k = 0; k < 2; ++k)
                        if ((pend >> k) & 1) {
                            int i = ln + (k << 6);
                            int r = i / 12, u = 288 + (i % 12);
                            v[k] = __hip_atomic_load(exb + r * HU + u,
                                                     __ATOMIC_RELAXED,
                                                     __HIP_MEMORY_SCOPE_AGENT);
                        }
                    unsigned got = 0;
                    #pragma unroll
                    for (int k = 0; k < 2; ++k) {
                        if (((pend >> k) & 1) && (int)(v[k] >> 32) >= t) {
                            int i = ln + (k << 6);
                            int r = i / 12, u = 288 + (i % 12);
                            int idx = r * HLB_STRIDE + u;
                            float f = __uint_as_float((unsigned)v[k]);
                            short hi = f2h(f);
                            h_hi[idx] = hi;
                            h_lo[idx] = f2h(f - h2f(hi));
                            got |= 1u << k;
                        }
                    }
                    pend &= ~got;
                    if (pend) __builtin_amdgcn_s_sleep(1);
                } while (pend);
            }
        }

        // ---- MFMA on own stripe: A hi/lo from LDS, B f16 from LDS ----
        f32x4 acc[5];
        #pragma unroll
        for (int nt = 0; nt < 5; ++nt) acc[nt] = (f32x4){0.f, 0.f, 0.f, 0.f};
        for (int s = 0; s < nks; ++s) {
            const int aoff = m * HLB_STRIDE + KSW * wv + 32 * s + quad * 8;
            f16x8 ah = *(const f16x8*)&h_hi[aoff];
            f16x8 al = *(const f16x8*)&h_lo[aoff];
            f16x8 bfr[5];
            #pragma unroll
            for (int nt = 0; nt < 5; ++nt)
                bfr[nt] = *(const f16x8*)&w_l[(((wv * 15) + (s * 5 + nt)) * 64 + ln) * 8];
            #pragma unroll
            for (int nt = 0; nt < 5; ++nt)
                acc[nt] = __builtin_amdgcn_mfma_f32_16x16x32_f16(
                    ah, bfr[nt], acc[nt], 0, 0, 0);
            #pragma unroll
            for (int nt = 0; nt < 5; ++nt)
                acc[nt] = __builtin_amdgcn_mfma_f32_16x16x32_f16(
                    al, bfr[nt], acc[nt], 0, 0, 0);
        }
        // C: row=quad*4+reg (lanes 0-31 -> rows 0-7), col=nt*16+m
        if (ln < 32) {
            #pragma unroll
            for (int nt = 0; nt < 5; ++nt)
                #pragma unroll
                for (int r4 = 0; r4 < 4; ++r4)
                    zp[par][wv][quad * 4 + r4][nt * 16 + m] = acc[nt][r4];
        }
        __syncthreads();   // the ONE barrier: zp(t) visible to gate lanes

        // ---- reduce 4 partials + gates + tagged publish (160 threads) ----
        if (gl) {
            const int b = r0 + g_r;
            float z4[4];
            #pragma unroll
            for (int gg = 0; gg < 4; ++gg) {
                int cidx = gg * UPW + g_u;
                z4[gg] = z_pre[gg] + zp[par][0][g_r][cidx] + zp[par][1][g_r][cidx]
                                   + zp[par][2][g_r][cidx] + zp[par][3][g_r][cidx];
            }
            float ig = sigm(z4[0]);
            float jg = tanh_(z4[1]);
            float fg = sigm(z4[2] + 1.0f);   // FORGET_BIAS
            float og = sigm(z4[3]);
            float c_new = c_reg * fg + ig * jg;
            float h_new = tanh_(c_new) * og;
            bool upd = (t < mylen);
            ho_reg = upd ? h_new : ho_reg;
            c_reg  = upd ? c_new : c_reg;
            // publish h_t (tag t+1, parity (t+1)&1) — fire & forget
            ull pk = ((ull)(unsigned)(t + 1) << 32) | (ull)__float_as_uint(ho_reg);
            __hip_atomic_store(
                ex + (((size_t)((t + 1) & 1) * GR + rg) * RPW + g_r) * HU + u0 + g_u,
                pk, __ATOMIC_RELAXED, __HIP_MEMORY_SCOPE_AGENT);
            if (tc == CHUNK - 1) hfin[(size_t)b * HU + u0 + g_u] = ho_reg;
        }
        // no trailing barrier: per-wave detect + the single barrier order all
        // h-stripe and zp reuse (see header proof).
    }
    if (gl) cst[(size_t)(r0 + g_r) * HU + u0 + g_u] = c_reg;
}

// ---------------------------------------------------------------------------
// Phase 3: logits = h_final @ W_dense + b_dense; log-softmax NLL; mean loss.
// One wave per batch row.
// ---------------------------------------------------------------------------
__global__ __launch_bounds__(64) void cls_kernel(
    const float* __restrict__ hfin, const float* __restrict__ Wd,
    const float* __restrict__ bd, const int* __restrict__ labels,
    float* __restrict__ out)
{
    const int b = blockIdx.x;
    const int ln = threadIdx.x;
    const float* h = hfin + (size_t)b * HU;
    float p0 = 0.f, p1 = 0.f, p2 = 0.f;
    for (int k = ln; k < HU; k += 64) {
        float hv = h[k];
        p0 += hv * Wd[k * 3 + 0];
        p1 += hv * Wd[k * 3 + 1];
        p2 += hv * Wd[k * 3 + 2];
    }
    #pragma unroll
    for (int off = 32; off > 0; off >>= 1) {
        p0 += __shfl_down(p0, off);
        p1 += __shfl_down(p1, off);
        p2 += __shfl_down(p2, off);
    }
    if (ln == 0) {
        float l0 = p0 + bd[0], l1 = p1 + bd[1], l2 = p2 + bd[2];
        float m = fmaxf(l0, fmaxf(l1, l2));
        float lse = m + logf(__expf(l0 - m) + __expf(l1 - m) + __expf(l2 - m));
        int lab = labels[b];
        float sel = (lab == 0) ? l0 : ((lab == 1) ? l1 : l2);
        float nll = lse - sel;
        out[1 + b * 3 + 0] = l0;
        out[1 + b * 3 + 1] = l1;
        out[1 + b * 3 + 2] = l2;
        atomicAdd(out, nll * (1.0f / BB));
    }
}

// ---------------------------------------------------------------------------
extern "C" void kernel_launch(void* const* d_in, const int* in_sizes, int n_in,
                              void* d_out, int out_size, void* d_ws, size_t ws_size,
                              hipStream_t stream) {
    const int*   ids  = (const int*)d_in[0];
    const int*   lens = (const int*)d_in[1];
    const int*   labs = (const int*)d_in[2];
    const float* emb  = (const float*)d_in[3];
    const float* Wl   = (const float*)d_in[4];
    const float* bl   = (const float*)d_in[5];
    const float* Wd   = (const float*)d_in[6];
    const float* bd   = (const float*)d_in[7];
    float* out = (float*)d_out;

    float* zx   = (float*)d_ws;
    ull*   ex   = (ull*)(zx + ZX_F);
    float* cst  = (float*)(ex + EX_W);
    float* hfin = cst + CST_F;

    {   // zero exchange tags / c state / out[0]
        int n = (int)((EX_W + 255) / 256);
        init_kernel<<<n, 256, 0, stream>>>(ex, cst, out);
    }
    for (int c = 0; c < NCHUNK; ++c) {
        int t0 = c * CHUNK;
        zx_gemm<<<dim3(32, 15), 256, 0, stream>>>(emb, ids, Wl, bl, zx, t0);
        lstm_rec<<<GR * GC, 256, 0, stream>>>(zx, Wl, lens, ex, cst, hfin, t0);
    }
    cls_kernel<<<BB, 64, 0, stream>>>(hfin, Wd, bd, labs, out);
}

// Round 12
// 2311.544 us; speedup vs baseline: 2.9947x; 1.1270x over previous
//
#include <hip/hip_runtime.h>
#include <hip/hip_bf16.h>
#include <math.h>

// Problem constants
#define VV   32000
#define DD   300
#define HU   300
#define NC   3
#define BB   128
#define TT   512
#define N4H  1200
#define CHUNK 64
#define NCHUNK (TT / CHUNK)

// Recurrent kernel partition
#define GC   15   // col groups (units)
#define GR   16   // row groups
#define RPW  8    // rows per WG (BB/GR)
#define UPW  20   // units per WG (HU/GC)
#define KSW  96   // k-window per wave (4 waves x 96 covers 300 w/ zero pad)
#define HLB_STRIDE 312            // h plane row stride in shorts (624B: 16B-aligned, 2-way bank alias = free)
#define HLB_SIZE   (16 * HLB_STRIDE + 32)

// Workspace layout: [zx (float)][ex (ulong, tagged h exchange)][cst][hfin]
static constexpr size_t ZX_F   = (size_t)BB * CHUNK * N4H;   // 9,830,400 floats
static constexpr size_t EX_W   = (size_t)2 * GR * RPW * HU;  // 76,800 ulongs
static constexpr size_t CST_F  = (size_t)BB * HU;            // 38,400 floats
static constexpr size_t HFIN_F = (size_t)BB * HU;            // 38,400 floats

typedef __attribute__((ext_vector_type(8))) short bf16x8;
typedef __attribute__((ext_vector_type(8))) _Float16 f16x8;
typedef __attribute__((ext_vector_type(4))) float f32x4;
typedef unsigned long long ull;

__device__ __forceinline__ short f2bf(float f) {
    unsigned u = __float_as_uint(f);
    u += 0x7fff + ((u >> 16) & 1);   // round-to-nearest-even
    return (short)(u >> 16);
}
__device__ __forceinline__ short f2h(float f) {   // float -> f16 bits (RTNE)
    _Float16 h = (_Float16)f;
    return *(short*)&h;
}
__device__ __forceinline__ float h2f(short s) {
    _Float16 h = *(_Float16*)&s;
    return (float)h;
}
__device__ __forceinline__ float sigm(float x) { return 1.f / (1.f + __expf(-x)); }
__device__ __forceinline__ float tanh_(float x) { return 1.f - 2.f / (__expf(2.f * x) + 1.f); }

// ---------------------------------------------------------------------------
// init: zero exchange tags, c state, out[0]  (ws is poisoned 0xAA every launch)
// ---------------------------------------------------------------------------
__global__ void init_kernel(ull* __restrict__ ex, float* __restrict__ cst,
                            float* __restrict__ out) {
    size_t i = (size_t)blockIdx.x * 256 + threadIdx.x;
    if (i < EX_W) ex[i] = 0ull;
    if (i < CST_F) cst[i] = 0.f;
    if (i == 0) out[0] = 0.f;
}

// ---------------------------------------------------------------------------
// Phase 1: zx[b][tc][n] = emb[ids[b][t0+tc]] @ W_lstm[0:300] + b_lstm   (bf16 MFMA)
// WG tile: M=256 rows, N=80 cols, K=320 (300 zero-padded). 4 waves, wave = 64x80.
// grid = (8192/256, 1200/80) = (32, 15)
// ---------------------------------------------------------------------------
__global__ __launch_bounds__(256) void zx_gemm(
    const float* __restrict__ emb, const int* __restrict__ ids,
    const float* __restrict__ Wl, const float* __restrict__ bl,
    float* __restrict__ zx, int t0)
{
    __shared__ short A_l[256 * 40];   // [row][k] pad 32->40 shorts
    __shared__ short B_l[80 * 40];    // [col][k] (transposed)
    __shared__ int   ids_l[256];

    const int tid = threadIdx.x;
    const int m0  = blockIdx.x * 256;
    const int n0  = blockIdx.y * 80;
    const int wv  = tid >> 6, ln = tid & 63;

    {   // per-row embedding id
        int m = m0 + tid;
        int b = m >> 6, tc = m & (CHUNK - 1);
        ids_l[tid] = ids[b * TT + t0 + tc];
    }

    f32x4 acc[4][5];
    for (int i = 0; i < 4; ++i)
        for (int j = 0; j < 5; ++j)
            acc[i][j] = (f32x4){0.f, 0.f, 0.f, 0.f};

    for (int k0 = 0; k0 < 320; k0 += 32) {
        __syncthreads();
        // stage A: 256 rows x 32 k, one row per thread (float4 x8, guard k<300)
        {
            const float* src = emb + (size_t)ids_l[tid] * DD;
            #pragma unroll
            for (int q = 0; q < 8; ++q) {
                int kg = k0 + q * 4;
                float4 v;
                if (kg < DD) v = *(const float4*)(src + kg);
                else         v = make_float4(0.f, 0.f, 0.f, 0.f);
                short4 s; s.x = f2bf(v.x); s.y = f2bf(v.y); s.z = f2bf(v.z); s.w = f2bf(v.w);
                *(short4*)&A_l[tid * 40 + q * 4] = s;
            }
        }
        // stage B (transposed): 80 cols x 32 k. thread: kk=tid>>3, 10 cols each
        {
            int kk = tid >> 3;
            int c0 = (tid & 7) * 10;
            int kg = k0 + kk;
            #pragma unroll
            for (int c = 0; c < 10; ++c) {
                float v = (kg < DD) ? Wl[(size_t)kg * N4H + n0 + c0 + c] : 0.f;
                B_l[(c0 + c) * 40 + kk] = f2bf(v);
            }
        }
        __syncthreads();
        // fragments + MFMA. A[m=lane&15][k=quad*8+j], B[k=quad*8+j][n=lane&15]
        const int koff = (ln >> 4) * 8;
        bf16x8 afr[4], bfr[5];
        #pragma unroll
        for (int mt = 0; mt < 4; ++mt) {
            int row = wv * 64 + mt * 16 + (ln & 15);
            afr[mt] = *(const bf16x8*)&A_l[row * 40 + koff];
        }
        #pragma unroll
        for (int nt = 0; nt < 5; ++nt) {
            int col = nt * 16 + (ln & 15);
            bfr[nt] = *(const bf16x8*)&B_l[col * 40 + koff];
        }
        #pragma unroll
        for (int mt = 0; mt < 4; ++mt)
            #pragma unroll
            for (int nt = 0; nt < 5; ++nt)
                acc[mt][nt] = __builtin_amdgcn_mfma_f32_16x16x32_bf16(
                    afr[mt], bfr[nt], acc[mt][nt], 0, 0, 0);
    }
    // epilogue: C row=(lane>>4)*4+reg, col=lane&15; add bias
    #pragma unroll
    for (int mt = 0; mt < 4; ++mt) {
        #pragma unroll
        for (int nt = 0; nt < 5; ++nt) {
            #pragma unroll
            for (int rg = 0; rg < 4; ++rg) {
                int row = m0 + wv * 64 + mt * 16 + (ln >> 4) * 4 + rg;
                int col = n0 + nt * 16 + (ln & 15);
                zx[(size_t)row * N4H + col] = acc[mt][nt][rg] + bl[col];
            }
        }
    }
}

// ---------------------------------------------------------------------------
// Phase 2: persistent recurrent kernel. 240 WGs = 16 row-groups x 15 col-groups.
// Recurrent GEMM: F16 MFMA with h-side split (absmax at 4.88e-4 output floor):
//   z = (h_hi + h_lo) @ W_f16,  h_hi = f16(h), h_lo = f16(h - h_hi)
// W_h f16 fragments live in LDS, fragment-ordered (R10: no VGPR spill).
// Per-wave K-window waiting + single barrier per step (R11).
//
// R12: SENTINEL-GATED POLLING. R11 post-mortem: every failing sweep re-loads
// the wave's full 768-word stripe -> ~23 MB/step of agent-scope loads across
// 240 WGs saturates the coherence fabric, inflating every round trip (why
// R10/R11 latency tweaks were neutral). Fix: wave first spins on <=6 SENTINEL
// words — one per producer WG overlapping its K-window (any of a producer's
// 160 words works as a presence signal; its gate lanes store within ~50 cyc
// of each other). Only then run the full stripe pass (now ~1 iteration) with
// per-word tag checks + straggler fallback for correctness (sentinels prove
// nothing about sibling words — tags still gate acceptance).
//
// Tag-ABA safety unchanged (transitive, per-wave): publish(s+2) > barrier(s+1)
// > all 4 waves detected tags s+1 over window-union = all 15 producers'
// s+1 publishes >= every consumer's step-s reads.
//
// NaN guard (R6): both h planes zeroed IN FULL once per dispatch, so wave 3's
// A reads of cols 300..319 are exact 0 (B=0 there; 0*0=0).
// ---------------------------------------------------------------------------
__global__ __launch_bounds__(256, 1) void lstm_rec(
    const float* __restrict__ zx, const float* __restrict__ Wl,
    const int* __restrict__ lens, ull* __restrict__ ex,
    float* __restrict__ cst, float* __restrict__ hfin, int t0)
{
    const int tid = threadIdx.x;
    const int wv  = tid >> 6, ln = tid & 63;
    const int rg  = blockIdx.x % GR;
    const int cgi = blockIdx.x / GR;
    const int r0  = rg * RPW;
    const int u0  = cgi * UPW;
    const int m   = ln & 15;           // MFMA row / col-in-tile
    const int quad = ln >> 4;

    // producers overlapping wave wv's K-window [96wv, 96wv+96)
    const int pstart_tbl[4] = {0, 4, 9, 14};
    const int np_tbl[4]     = {5, 6, 6, 1};
    const int pstart = pstart_tbl[wv];
    const int np     = np_tbl[wv];

    __shared__ short h_hi[HLB_SIZE];        // f16 hi plane of h_{t-1}
    __shared__ short h_lo[HLB_SIZE];        // f16 lo plane of h_{t-1}
    __shared__ float zp[2][4][RPW][84];     // parity x wave k-partials (pad 80->84)
    __shared__ short w_l[4 * 15 * 64 * 8];  // f16 W_h fragments, frag-ordered

    // ---- one-time: pack W_h f16 B-fragments into LDS ----
    // B[k=quad*8+j][n=lane&15]; frag f = s*5+nt covers kstep s, ntile nt.
    #pragma unroll
    for (int s = 0; s < 3; ++s) {
        #pragma unroll
        for (int nt = 0; nt < 5; ++nt) {
            int c    = nt * 16 + m;            // 0..79 within WG cols
            int gate = c / 20;
            int wcol = 300 * gate + u0 + (c % 20);
            f16x8 b;
            #pragma unroll
            for (int j = 0; j < 8; ++j) {
                int k = KSW * wv + 32 * s + quad * 8 + j;
                float v = (k < HU) ? Wl[(size_t)(DD + k) * N4H + wcol] : 0.f;
                b[j] = (_Float16)v;
            }
            *(f16x8*)&w_l[(((wv * 15) + (s * 5 + nt)) * 64 + ln) * 8] = b;
        }
    }
    const int nks = (wv == 3) ? 1 : 3;   // wave 3: only kstep 0 has real k

    // zero BOTH h planes in full once per dispatch (NaN guard + h0 = 0)
    for (int i = tid; i < HLB_SIZE; i += 256) { h_hi[i] = 0; h_lo[i] = 0; }

    // gate role (tid < 160): u = tid%20, r = tid/20; c/h_old in registers
    const int g_u = tid % UPW, g_r = tid / UPW;
    const bool gl = (tid < RPW * UPW);
    float c_reg = 0.f, ho_reg = 0.f;
    int mylen = 0;
    if (gl) {
        c_reg = cst[(size_t)(r0 + g_r) * HU + u0 + g_u];
        mylen = lens[r0 + g_r];
        if (t0 > 0) {   // reload own h_{t0-1} (tag t0, parity t0&1) from last dispatch
            ull v = __hip_atomic_load(
                ex + (((size_t)(t0 & 1) * GR + rg) * RPW + g_r) * HU + u0 + g_u,
                __ATOMIC_RELAXED, __HIP_MEMORY_SCOPE_AGENT);
            ho_reg = __uint_as_float((unsigned)v);
        }
    }
    __syncthreads();   // h-plane zero + w_l pack visible before first step

    for (int tc = 0; tc < CHUNK; ++tc) {
        const int t = t0 + tc;
        const int par = t & 1;

        // prefetch zx for this step (independent of h)
        float z_pre[4];
        if (gl) {
            const float* zrow = zx + ((size_t)(r0 + g_r) * CHUNK + tc) * N4H;
            #pragma unroll
            for (int gg = 0; gg < 4; ++gg)
                z_pre[gg] = zrow[300 * gg + u0 + g_u];
        }

        // ---- per-wave stage of OWN K-window stripe (no barrier after) ----
        if (t > 0) {
            const ull* exb = ex + ((size_t)par * GR + rg) * (RPW * HU);

            // phase 1: sentinel spin — lane l polls producer pstart+l (word
            // r=0, u=20p). Cheap (<=6 lines/wave/sweep vs 96 for a full pass).
            if (ln < np) {
                const ull* sp = exb + (pstart + ln) * UPW;
                while ((int)(__hip_atomic_load(sp, __ATOMIC_RELAXED,
                             __HIP_MEMORY_SCOPE_AGENT) >> 32) < t)
                    __builtin_amdgcn_s_sleep(1);
            }

            // phase 2+3: full stripe pass (typically 1 sweep) + straggler poll
            if (wv < 3) {
                // 768 words: i = ln + 64k, r = i/96, u = 96*wv + i%96
                unsigned pend = 0xFFFu;
                do {
                    ull v[12];
                    #pragma unroll
                    for (int k = 0; k < 12; ++k)
                        if ((pend >> k) & 1) {
                            int i = ln + (k << 6);
                            int r = i / 96, u = KSW * wv + (i % 96);
                            v[k] = __hip_atomic_load(exb + r * HU + u,
                                                     __ATOMIC_RELAXED,
                                                     __HIP_MEMORY_SCOPE_AGENT);
                        }
                    unsigned got = 0;
                    #pragma unroll
                    for (int k = 0; k < 12; ++k) {
                        if (((pend >> k) & 1) && (int)(v[k] >> 32) >= t) {
                            int i = ln + (k << 6);
                            int r = i / 96, u = KSW * wv + (i % 96);
                            int idx = r * HLB_STRIDE + u;
                            float f = __uint_as_float((unsigned)v[k]);
                            short hi = f2h(f);
                            h_hi[idx] = hi;
                            h_lo[idx] = f2h(f - h2f(hi));
                            got |= 1u << k;
                        }
                    }
                    pend &= ~got;
                    if (pend) __builtin_amdgcn_s_sleep(1);
                } while (pend);
            } else {
                // 96 words: i = ln + 64k (i<96), r = i/12, u = 288 + i%12
                unsigned pend = (ln < 32) ? 0x3u : 0x1u;
                do {
                    ull v[2];
                    #pragma unroll
                    for (int k = 0; k < 2; ++k)
                        if ((pend >> k) & 1) {
                            int i = ln + (k << 6);
                            int r = i / 12, u = 288 + (i % 12);
                            v[k] = __hip_atomic_load(exb + r * HU + u,
                                                     __ATOMIC_RELAXED,
                                                     __HIP_MEMORY_SCOPE_AGENT);
                        }
                    unsigned got = 0;
                    #pragma unroll
                    for (int k = 0; k < 2; ++k) {
                        if (((pend >> k) & 1) && (int)(v[k] >> 32) >= t) {
                            int i = ln + (k << 6);
                            int r = i / 12, u = 288 + (i % 12);
                            int idx = r * HLB_STRIDE + u;
                            float f = __uint_as_float((unsigned)v[k]);
                            short hi = f2h(f);
                            h_hi[idx] = hi;
                            h_lo[idx] = f2h(f - h2f(hi));
                            got |= 1u << k;
                        }
                    }
                    pend &= ~got;
                    if (pend) __builtin_amdgcn_s_sleep(1);
                } while (pend);
            }
        }

        // ---- MFMA on own stripe: A hi/lo from LDS, B f16 from LDS ----
        f32x4 acc[5];
        #pragma unroll
        for (int nt = 0; nt < 5; ++nt) acc[nt] = (f32x4){0.f, 0.f, 0.f, 0.f};
        for (int s = 0; s < nks; ++s) {
            const int aoff = m * HLB_STRIDE + KSW * wv + 32 * s + quad * 8;
            f16x8 ah = *(const f16x8*)&h_hi[aoff];
            f16x8 al = *(const f16x8*)&h_lo[aoff];
            f16x8 bfr[5];
            #pragma unroll
            for (int nt = 0; nt < 5; ++nt)
                bfr[nt] = *(const f16x8*)&w_l[(((wv * 15) + (s * 5 + nt)) * 64 + ln) * 8];
            #pragma unroll
            for (int nt = 0; nt < 5; ++nt)
                acc[nt] = __builtin_amdgcn_mfma_f32_16x16x32_f16(
                    ah, bfr[nt], acc[nt], 0, 0, 0);
            #pragma unroll
            for (int nt = 0; nt < 5; ++nt)
                acc[nt] = __builtin_amdgcn_mfma_f32_16x16x32_f16(
                    al, bfr[nt], acc[nt], 0, 0, 0);
        }
        // C: row=quad*4+reg (lanes 0-31 -> rows 0-7), col=nt*16+m
        if (ln < 32) {
            #pragma unroll
            for (int nt = 0; nt < 5; ++nt)
                #pragma unroll
                for (int r4 = 0; r4 < 4; ++r4)
                    zp[par][wv][quad * 4 + r4][nt * 16 + m] = acc[nt][r4];
        }
        __syncthreads();   // the ONE barrier: zp(t) visible to gate lanes

        // ---- reduce 4 partials + gates + tagged publish (160 threads) ----
        if (gl) {
            const int b = r0 + g_r;
            float z4[4];
            #pragma unroll
            for (int gg = 0; gg < 4; ++gg) {
                int cidx = gg * UPW + g_u;
                z4[gg] = z_pre[gg] + zp[par][0][g_r][cidx] + zp[par][1][g_r][cidx]
                                   + zp[par][2][g_r][cidx] + zp[par][3][g_r][cidx];
            }
            float ig = sigm(z4[0]);
            float jg = tanh_(z4[1]);
            float fg = sigm(z4[2] + 1.0f);   // FORGET_BIAS
            float og = sigm(z4[3]);
            float c_new = c_reg * fg + ig * jg;
            float h_new = tanh_(c_new) * og;
            bool upd = (t < mylen);
            ho_reg = upd ? h_new : ho_reg;
            c_reg  = upd ? c_new : c_reg;
            // publish h_t (tag t+1, parity (t+1)&1) — fire & forget
            ull pk = ((ull)(unsigned)(t + 1) << 32) | (ull)__float_as_uint(ho_reg);
            __hip_atomic_store(
                ex + (((size_t)((t + 1) & 1) * GR + rg) * RPW + g_r) * HU + u0 + g_u,
                pk, __ATOMIC_RELAXED, __HIP_MEMORY_SCOPE_AGENT);
            if (tc == CHUNK - 1) hfin[(size_t)b * HU + u0 + g_u] = ho_reg;
        }
        // no trailing barrier: per-wave detect + the single barrier order all
        // h-stripe and zp reuse (see header proof).
    }
    if (gl) cst[(size_t)(r0 + g_r) * HU + u0 + g_u] = c_reg;
}

// ---------------------------------------------------------------------------
// Phase 3: logits = h_final @ W_dense + b_dense; log-softmax NLL; mean loss.
// One wave per batch row.
// ---------------------------------------------------------------------------
__global__ __launch_bounds__(64) void cls_kernel(
    const float* __restrict__ hfin, const float* __restrict__ Wd,
    const float* __restrict__ bd, const int* __restrict__ labels,
    float* __restrict__ out)
{
    const int b = blockIdx.x;
    const int ln = threadIdx.x;
    const float* h = hfin + (size_t)b * HU;
    float p0 = 0.f, p1 = 0.f, p2 = 0.f;
    for (int k = ln; k < HU; k += 64) {
        float hv = h[k];
        p0 += hv * Wd[k * 3 + 0];
        p1 += hv * Wd[k * 3 + 1];
        p2 += hv * Wd[k * 3 + 2];
    }
    #pragma unroll
    for (int off = 32; off > 0; off >>= 1) {
        p0 += __shfl_down(p0, off);
        p1 += __shfl_down(p1, off);
        p2 += __shfl_down(p2, off);
    }
    if (ln == 0) {
        float l0 = p0 + bd[0], l1 = p1 + bd[1], l2 = p2 + bd[2];
        float m = fmaxf(l0, fmaxf(l1, l2));
        float lse = m + logf(__expf(l0 - m) + __expf(l1 - m) + __expf(l2 - m));
        int lab = labels[b];
        float sel = (lab == 0) ? l0 : ((lab == 1) ? l1 : l2);
        float nll = lse - sel;
        out[1 + b * 3 + 0] = l0;
        out[1 + b * 3 + 1] = l1;
        out[1 + b * 3 + 2] = l2;
        atomicAdd(out, nll * (1.0f / BB));
    }
}

// ---------------------------------------------------------------------------
extern "C" void kernel_launch(void* const* d_in, const int* in_sizes, int n_in,
                              void* d_out, int out_size, void* d_ws, size_t ws_size,
                              hipStream_t stream) {
    const int*   ids  = (const int*)d_in[0];
    const int*   lens = (const int*)d_in[1];
    const int*   labs = (const int*)d_in[2];
    const float* emb  = (const float*)d_in[3];
    const float* Wl   = (const float*)d_in[4];
    const float* bl   = (const float*)d_in[5];
    const float* Wd   = (const float*)d_in[6];
    const float* bd   = (const float*)d_in[7];
    float* out = (float*)d_out;

    float* zx   = (float*)d_ws;
    ull*   ex   = (ull*)(zx + ZX_F);
    float* cst  = (float*)(ex + EX_W);
    float* hfin = cst + CST_F;

    {   // zero exchange tags / c state / out[0]
        int n = (int)((EX_W + 255) / 256);
        init_kernel<<<n, 256, 0, stream>>>(ex, cst, out);
    }
    for (int c = 0; c < NCHUNK; ++c) {
        int t0 = c * CHUNK;
        zx_gemm<<<dim3(32, 15), 256, 0, stream>>>(emb, ids, Wl, bl, zx, t0);
        lstm_rec<<<GR * GC, 256, 0, stream>>>(zx, Wl, lens, ex, cst, hfin, t0);
    }
    cls_kernel<<<BB, 64, 0, stream>>>(hfin, Wd, bd, labs, out);
}